// Round 14
// baseline (410.734 us; speedup 1.0000x reference)
//
#include <hip/hip_runtime.h>

#define N_NODES 50000
#define E_RAW_N 800000
#define E_TOT   850000
#define F_IN_K  500
#define HID     160
#define XSTR    184   // packed row: 160 bf16 cols + 5 f32 a_s (+pad), 16B-aligned

using short8 = __attribute__((ext_vector_type(8))) short;
using f32x4  = __attribute__((ext_vector_type(4))) float;

__device__ __forceinline__ float b2f(unsigned short u) {
  union { unsigned int i; float f; } v; v.i = ((unsigned int)u) << 16; return v.f;
}
__device__ __forceinline__ unsigned short f2b(float f) {
  union { float f; unsigned int i; } v; v.f = f;
  unsigned int i = v.i;
  unsigned int lsb = (i >> 16) & 1u;
  i += 0x7fffu + lsb;
  return (unsigned short)(i >> 16);
}

__device__ __forceinline__ float wsum(float x) {
  #pragma unroll
  for (int o = 32; o; o >>= 1) x += __shfl_xor(x, o, 64);
  return x;
}
__device__ __forceinline__ float wmax(float x) {
  #pragma unroll
  for (int o = 32; o; o >>= 1) x = fmaxf(x, __shfl_xor(x, o, 64));
  return x;
}
__device__ __forceinline__ float lrelu2(float x) { return x > 0.f ? x : 0.2f * x; }

// ---------------- edge dtype detection (int64 vs int32 hedge) ----------------
__global__ void detect_kernel(const int* __restrict__ ei, int* __restrict__ flag) {
  if (threadIdx.x == 0 && blockIdx.x == 0) {
    int allz = 1;
    for (int i = 1; i < 128; i += 2) if (ei[i] != 0) { allz = 0; break; }
    *flag = allz;  // 1 => int64 layout
  }
}
__device__ __forceinline__ int edge_src(const int* ei, int wide, int e) {
  return wide ? ei[2 * e] : ei[e];
}
__device__ __forceinline__ int edge_dst(const int* ei, int wide, int e) {
  return wide ? ei[2 * (E_RAW_N + e)] : ei[E_RAW_N + e];
}

// ------- weight pre-convert (all 3 weights in one launch): f32 -> bf16 -------
__global__ __launch_bounds__(256) void convert_all(
    const float* __restrict__ W1, const float* __restrict__ W2, const float* __restrict__ Wm,
    unsigned short* __restrict__ Bt1, unsigned short* __restrict__ Bt2,
    unsigned short* __restrict__ Btm)
{
  const int i = blockIdx.x * 256 + threadIdx.x;
  if (i < HID * 512) {
    const int c = i / 512, k = i % 512;
    Bt1[i] = f2b((k < F_IN_K) ? W1[(long)k * HID + c] : 0.f);
  }
  if (i < HID * 192) {
    const int c = i / 192, k = i % 192;
    Bt2[i] = f2b((k < HID) ? W2[(long)k * HID + c] : 0.f);
    Btm[i] = f2b((k < HID) ? Wm[(long)k * HID + c] : 0.f);
  }
}

// ---------------- GEMM: [M,160] = A[M,K] @ B, LDS-staged B, pipelined --------
// block = 4 waves (256 thr), BM=32; wave (rg,cg) = rows rg*16..+16, col-tiles
// cg*5..+5. acc[5] (20 VGPR) + rb[5] (40) -> ~110 VGPR, 4-5 waves/SIMD.
// Duplicate A reads between col-waves hit L1. MODE 2 att dots combined via LDS.
// AT=float: A converted to bf16 in-register. AT=ushort: direct short8 loads.
// MODE 1: +bias, leaky(0.01), C f32 (stride 160).
// MODE 2: packed row out (stride XSTR): bf16 cols + fused att-dot a_s; a_d arr.
template<typename AT, int K, int KPAD, int BK, int MODE>
__global__ __launch_bounds__(256) void gemm_lds(
    const AT* __restrict__ A, const unsigned short* __restrict__ Bt,
    float* __restrict__ C, unsigned short* __restrict__ Ch,
    const float* __restrict__ bias,
    const float* __restrict__ att_s, const float* __restrict__ att_d,
    float* __restrict__ a_d)
{
  constexpr bool AB16 = (sizeof(AT) == 2);
  constexpr int LSTR = BK + 8;
  constexpr int CHUNKS = KPAD / BK;
  constexpr int KSC = BK / 32;
  constexpr int ROWU = BK / 8;
  constexpr int UNITS = HID * ROWU;
  static_assert(UNITS % 256 == 0, "units must tile threads");
  constexpr int UPT = UNITS / 256;
  __shared__ __align__(16) unsigned short Bs[HID][LSTR];
  __shared__ float attP[32][6][2];

  const int t = threadIdx.x;
  const int l = t & 63;
  const int w = t >> 6;
  const int rg = w & 1;         // row-group
  const int cg = w >> 1;        // col-group
  const int m = l & 15;
  const int kgrp = (l >> 4) * 8;
  const int rbase = blockIdx.x * 32 + rg * 16;
  const int arow = (rbase + m < N_NODES) ? rbase + m : N_NODES - 1;
  const AT* Arow = A + (long)arow * K;

  f32x4 acc[5];
  #pragma unroll
  for (int i = 0; i < 5; ++i) acc[i] = (f32x4){0.f, 0.f, 0.f, 0.f};

  short8 rb[UPT];
  float  arF[KSC][8], arF2[KSC][8];
  short8 arS[KSC], arS2[KSC];

  auto loadB = [&](int cc, short8* dst) {
    #pragma unroll
    for (int i = 0; i < UPT; ++i) {
      const int u = i * 256 + t;
      const int c = u / ROWU;
      const int k8 = u % ROWU;
      dst[i] = *(const short8*)(Bt + (long)c * KPAD + cc * BK + k8 * 8);
    }
  };
  auto loadA = [&](int cc, float aF[KSC][8], short8* aS) {
    #pragma unroll
    for (int ks = 0; ks < KSC; ++ks) {
      const int kb = cc * BK + ks * 32 + kgrp;
      if constexpr (AB16) {
        short8 v = (short8){0,0,0,0,0,0,0,0};
        if (kb + 8 <= K) v = *(const short8*)(Arow + kb);
        else if (kb < K) {
          #pragma unroll
          for (int j = 0; j < 8; ++j) v[j] = (kb + j < K) ? (short)Arow[kb + j] : (short)0;
        }
        aS[ks] = v;
      } else {
        if (kb + 8 <= K) {
          const float4 a0 = *(const float4*)(Arow + kb);
          const float4 a1 = *(const float4*)(Arow + kb + 4);
          aF[ks][0]=a0.x; aF[ks][1]=a0.y; aF[ks][2]=a0.z; aF[ks][3]=a0.w;
          aF[ks][4]=a1.x; aF[ks][5]=a1.y; aF[ks][6]=a1.z; aF[ks][7]=a1.w;
        } else {
          #pragma unroll
          for (int j = 0; j < 8; ++j) aF[ks][j] = (kb + j < K) ? (float)Arow[kb + j] : 0.f;
        }
      }
    }
  };

  loadB(0, rb);
  loadA(0, arF, arS);

  for (int cc = 0; cc < CHUNKS; ++cc) {
    __syncthreads();
    #pragma unroll
    for (int i = 0; i < UPT; ++i) {
      const int u = i * 256 + t;
      const int c = u / ROWU;
      const int k8 = u % ROWU;
      *(short8*)&Bs[c][k8 * 8] = rb[i];
    }
    __syncthreads();
    if (cc + 1 < CHUNKS) {
      loadB(cc + 1, rb);
      loadA(cc + 1, arF2, arS2);
      __builtin_amdgcn_sched_barrier(0);
    }
    __builtin_amdgcn_s_setprio(1);
    #pragma unroll
    for (int ks = 0; ks < KSC; ++ks) {
      short8 ah;
      if constexpr (AB16) {
        ah = arS[ks];
      } else {
        #pragma unroll
        for (int j = 0; j < 8; ++j) ah[j] = (short)f2b(arF[ks][j]);
      }
      #pragma unroll
      for (int ct = 0; ct < 5; ++ct) {
        const short8 bh = *(const short8*)&Bs[(cg * 5 + ct) * 16 + m][ks * 32 + kgrp];
        acc[ct] = __builtin_amdgcn_mfma_f32_16x16x32_bf16(ah, bh, acc[ct], 0, 0, 0);
      }
    }
    __builtin_amdgcn_s_setprio(0);
    if (cc + 1 < CHUNKS) {
      #pragma unroll
      for (int ks = 0; ks < KSC; ++ks) {
        if constexpr (AB16) arS[ks] = arS2[ks];
        else {
          #pragma unroll
          for (int j = 0; j < 8; ++j) arF[ks][j] = arF2[ks][j];
        }
      }
    }
  }

  const int crow0 = rbase + (l >> 4) * 4;

  if (MODE == 2) {
    // fused attention dots: per-wave partials over its 5 col-tiles, cross-wave
    // combine via LDS (col-groups 0 and 1 both cover each row).
    float vsr[4], vdr[4];
    #pragma unroll
    for (int r = 0; r < 4; ++r) {
      float ps[5] = {0.f,0.f,0.f,0.f,0.f}, pd[5] = {0.f,0.f,0.f,0.f,0.f};
      #pragma unroll
      for (int ct = 0; ct < 5; ++ct) {
        const int gct = cg * 5 + ct;
        const int h = gct >> 1;        // head of this col-tile
        ps[h] += acc[ct][r] * att_s[gct * 16 + m];
        pd[h] += acc[ct][r] * att_d[gct * 16 + m];
      }
      #pragma unroll
      for (int h = 0; h < 5; ++h) {
        #pragma unroll
        for (int o = 1; o < 16; o <<= 1) {
          ps[h] += __shfl_xor(ps[h], o, 64);
          pd[h] += __shfl_xor(pd[h], o, 64);
        }
      }
      vsr[r] = m == 0 ? ps[0] : m == 1 ? ps[1] : m == 2 ? ps[2] : m == 3 ? ps[3] : ps[4];
      vdr[r] = m == 0 ? pd[0] : m == 1 ? pd[1] : m == 2 ? pd[2] : m == 3 ? pd[3] : pd[4];
      const int row_local = rg * 16 + (l >> 4) * 4 + r;
      if (cg == 1 && m < 5) {
        attP[row_local][m][0] = vsr[r];
        attP[row_local][m][1] = vdr[r];
      }
    }
    __syncthreads();
    if (cg == 0 && m < 5) {
      #pragma unroll
      for (int r = 0; r < 4; ++r) {
        const int crow = crow0 + r;
        const int row_local = rg * 16 + (l >> 4) * 4 + r;
        if (crow < N_NODES) {
          ((float*)(Ch + (long)crow * XSTR + 160))[m] = vsr[r] + attP[row_local][m][0];
          a_d[crow * 5 + m] = vdr[r] + attP[row_local][m][1];
        }
      }
    }
  }

  #pragma unroll
  for (int r = 0; r < 4; ++r) {
    const int crow = crow0 + r;
    if (crow < N_NODES) {
      #pragma unroll
      for (int ct = 0; ct < 5; ++ct) {
        const int col = (cg * 5 + ct) * 16 + m;
        float v = acc[ct][r];
        if (MODE == 1) { v += bias[col]; v = v > 0.f ? v : 0.01f * v; }
        if (MODE == 2) Ch[(long)crow * XSTR + col] = f2b(v);
        else           C[(long)crow * HID + col] = v;
      }
    }
  }
}

// ---------------- CSR build ---------------------------------------------------
__global__ __launch_bounds__(256) void count_kernel(const int* __restrict__ ei,
    const int* __restrict__ flag, int* __restrict__ deg) {
  const int e = blockIdx.x * 256 + threadIdx.x;
  if (e >= E_TOT) return;
  const int wide = *flag;
  const int d = (e < E_RAW_N) ? edge_dst(ei, wide, e) : (e - E_RAW_N);
  atomicAdd(&deg[d], 1);
}

#define SCAN_CHUNK 49  // 1024*49 = 50176 >= 50000
__global__ __launch_bounds__(1024) void scan_kernel(const int* __restrict__ deg, int* __restrict__ off) {
  __shared__ int wtot[16];
  const int t = threadIdx.x;
  const int lane = t & 63, wid = t >> 6;
  const int base = t * SCAN_CHUNK;
  int local[SCAN_CHUNK];
  int sum = 0;
  #pragma unroll
  for (int i = 0; i < SCAN_CHUNK; ++i) {
    const int idx = base + i;
    const int v = (idx < N_NODES) ? deg[idx] : 0;
    local[i] = sum;
    sum += v;
  }
  int inc = sum;
  #pragma unroll
  for (int o = 1; o < 64; o <<= 1) {
    const int y = __shfl_up(inc, o, 64);
    if (lane >= o) inc += y;
  }
  if (lane == 63) wtot[wid] = inc;
  __syncthreads();
  if (wid == 0 && lane < 16) {
    const int v = wtot[lane];
    int inc2 = v;
    #pragma unroll
    for (int o = 1; o < 16; o <<= 1) {
      const int y = __shfl_up(inc2, o, 64);
      if (lane >= o) inc2 += y;
    }
    wtot[lane] = inc2 - v;  // exclusive
  }
  __syncthreads();
  const int pre = wtot[wid] + (inc - sum);
  #pragma unroll
  for (int i = 0; i < SCAN_CHUNK; ++i) {
    const int idx = base + i;
    if (idx < N_NODES) off[idx] = pre + local[i];
  }
  if (t == 1023) off[N_NODES] = E_TOT;
}

__global__ __launch_bounds__(256) void fill_kernel(const int* __restrict__ ei,
    const int* __restrict__ flag, const int* __restrict__ off,
    int* __restrict__ fillc, int* __restrict__ csr_src, int* __restrict__ csr_eid) {
  const int e = blockIdx.x * 256 + threadIdx.x;
  if (e >= E_TOT) return;
  const int wide = *flag;
  int s, d;
  if (e < E_RAW_N) { s = edge_src(ei, wide, e); d = edge_dst(ei, wide, e); }
  else { s = e - E_RAW_N; d = s; }
  const int p = off[d] + atomicAdd(&fillc[d], 1);
  csr_src[p] = s;
  csr_eid[p] = e;
}

// ---------------- fused per-node segment-softmax + aggregation ---------------
template<int DO_LN>
__global__ __launch_bounds__(256) void node_kernel(
    const int* __restrict__ off_, const int* __restrict__ csr_src, const int* __restrict__ csr_eid,
    const unsigned short* __restrict__ xlh,
    const float* __restrict__ a_d,
    float* __restrict__ alpha_out,
    const float* __restrict__ bias,
    const float* __restrict__ gamma_, const float* __restrict__ beta_,
    unsigned short* __restrict__ hout)
{
  __shared__ int   srcS[4][64];
  __shared__ float alS[4][64][6];

  const int w = threadIdx.x >> 6;
  const int l = threadIdx.x & 63;
  const int n = blockIdx.x * 4 + w;
  if (n >= N_NODES) return;
  const int off = off_[n];
  const int deg = off_[n + 1] - off;

  const float ad0 = a_d[n*5+0], ad1 = a_d[n*5+1], ad2 = a_d[n*5+2], ad3 = a_d[n*5+3], ad4 = a_d[n*5+4];
  const int hA = l >> 4;  // head for cols 2l, 2l+1
  float accx = 0.f, accy = 0.f, accz = 0.f;

  if (deg <= 64) {
    // ---- register softmax (no max pass): one lane per edge ----
    int src = 0, eid = 0;
    float e0 = 0.f, e1 = 0.f, e2 = 0.f, e3 = 0.f, e4 = 0.f;
    if (l < deg) {
      src = csr_src[off + l];
      eid = csr_eid[off + l];
      const float* ap = (const float*)(xlh + (unsigned)src * XSTR + 160);
      e0 = __expf(lrelu2(ap[0] + ad0));
      e1 = __expf(lrelu2(ap[1] + ad1));
      e2 = __expf(lrelu2(ap[2] + ad2));
      e3 = __expf(lrelu2(ap[3] + ad3));
      e4 = __expf(lrelu2(ap[4] + ad4));
    }
    const float i0 = 1.f / (wsum(e0) + 1e-16f), i1 = 1.f / (wsum(e1) + 1e-16f),
                i2 = 1.f / (wsum(e2) + 1e-16f), i3 = 1.f / (wsum(e3) + 1e-16f),
                i4 = 1.f / (wsum(e4) + 1e-16f);
    const float a0 = e0 * i0, a1 = e1 * i1, a2 = e2 * i2, a3 = e3 * i3, a4 = e4 * i4;
    if (l < deg) {
      float* aw = alpha_out + (long)eid * 5;
      aw[0] = a0; aw[1] = a1; aw[2] = a2; aw[3] = a3; aw[4] = a4;
    }
    srcS[w][l] = src;
    alS[w][l][0] = a0; alS[w][l][1] = a1; alS[w][l][2] = a2;
    alS[w][l][3] = a3; alS[w][l][4] = a4;

    const int degR = (deg + 7) & ~7;
    const unsigned cx = 2 * l, cz = 128 + l;
    for (int s0 = 0; s0 < degR; s0 += 8) {
      int sr[8]; float aA[8], aB[8];
      #pragma unroll
      for (int j = 0; j < 8; ++j) {
        sr[j] = srcS[w][s0 + j];
        aA[j] = alS[w][s0 + j][hA];
        aB[j] = alS[w][s0 + j][4];
      }
      ushort2 u2[8]; unsigned short z[8];
      #pragma unroll
      for (int j = 0; j < 8; ++j) {
        const unsigned xb = (unsigned)sr[j] * XSTR;
        u2[j] = *(const ushort2*)(xlh + xb + cx);
        if (l < 32) z[j] = xlh[xb + cz];
      }
      #pragma unroll
      for (int j = 0; j < 8; ++j) {
        accx += b2f(u2[j].x) * aA[j];
        accy += b2f(u2[j].y) * aA[j];
        if (l < 32) accz += b2f(z[j]) * aB[j];
      }
    }
  } else {
    // ---- slow path (rare): 3-pass over segment ----
    float m0 = -1e30f, m1 = -1e30f, m2 = -1e30f, m3 = -1e30f, m4 = -1e30f;
    for (int s = l; s < deg; s += 64) {
      const float* ap = (const float*)(xlh + (unsigned)csr_src[off + s] * XSTR + 160);
      m0 = fmaxf(m0, lrelu2(ap[0] + ad0));
      m1 = fmaxf(m1, lrelu2(ap[1] + ad1));
      m2 = fmaxf(m2, lrelu2(ap[2] + ad2));
      m3 = fmaxf(m3, lrelu2(ap[3] + ad3));
      m4 = fmaxf(m4, lrelu2(ap[4] + ad4));
    }
    m0 = wmax(m0); m1 = wmax(m1); m2 = wmax(m2); m3 = wmax(m3); m4 = wmax(m4);
    float s0 = 0.f, s1 = 0.f, s2 = 0.f, s3 = 0.f, s4 = 0.f;
    for (int s = l; s < deg; s += 64) {
      const float* ap = (const float*)(xlh + (unsigned)csr_src[off + s] * XSTR + 160);
      s0 += __expf(lrelu2(ap[0] + ad0) - m0);
      s1 += __expf(lrelu2(ap[1] + ad1) - m1);
      s2 += __expf(lrelu2(ap[2] + ad2) - m2);
      s3 += __expf(lrelu2(ap[3] + ad3) - m3);
      s4 += __expf(lrelu2(ap[4] + ad4) - m4);
    }
    const float i0 = 1.f / (wsum(s0) + 1e-16f), i1 = 1.f / (wsum(s1) + 1e-16f),
                i2 = 1.f / (wsum(s2) + 1e-16f), i3 = 1.f / (wsum(s3) + 1e-16f),
                i4 = 1.f / (wsum(s4) + 1e-16f);
    const float adA = hA == 0 ? ad0 : hA == 1 ? ad1 : hA == 2 ? ad2 : ad3;
    const float mA  = hA == 0 ? m0  : hA == 1 ? m1  : hA == 2 ? m2  : m3;
    const float iA  = hA == 0 ? i0  : hA == 1 ? i1  : hA == 2 ? i2  : i3;
    float adw = 0.f, mw = 0.f, iw = 0.f;
    if (l < 5) {
      adw = l == 0 ? ad0 : l == 1 ? ad1 : l == 2 ? ad2 : l == 3 ? ad3 : ad4;
      mw  = l == 0 ? m0  : l == 1 ? m1  : l == 2 ? m2  : l == 3 ? m3  : m4;
      iw  = l == 0 ? i0  : l == 1 ? i1  : l == 2 ? i2  : l == 3 ? i3  : i4;
    }
    for (int s = 0; s < deg; ++s) {
      const int p = off + s;
      const int srcs = csr_src[p];
      const unsigned xb = (unsigned)srcs * XSTR;
      const float* ap = (const float*)(xlh + xb + 160);
      const float aA = __expf(lrelu2(ap[hA] + adA) - mA) * iA;
      const ushort2 u2 = *(const ushort2*)(xlh + xb + 2 * l);
      accx += b2f(u2.x) * aA;
      accy += b2f(u2.y) * aA;
      if (l < 32) {
        const float aC = __expf(lrelu2(ap[4] + ad4) - m4) * i4;
        accz += b2f(xlh[xb + 128 + l]) * aC;
      }
      if (l < 5) {
        alpha_out[(long)csr_eid[p] * 5 + l] = __expf(lrelu2(ap[l] + adw) - mw) * iw;
      }
    }
  }

  // epilogue (bf16 store)
  const int c0 = 2 * l, c2 = 128 + l;
  float v0 = accx + bias[c0];     v0 = v0 > 0.f ? v0 : 0.01f * v0;
  float v1 = accy + bias[c0 + 1]; v1 = v1 > 0.f ? v1 : 0.01f * v1;
  float v2 = 0.f;
  if (l < 32) { v2 = accz + bias[c2]; v2 = v2 > 0.f ? v2 : 0.01f * v2; }

  const long hb = (long)n * HID;
  if (DO_LN) {
    const float tot = wsum(v0 + v1 + v2);
    const float mean = tot * (1.f / 160.f);
    const float d0 = v0 - mean, d1 = v1 - mean;
    float sq = d0 * d0 + d1 * d1;
    float d2 = 0.f;
    if (l < 32) { d2 = v2 - mean; sq += d2 * d2; }
    const float var = wsum(sq) * (1.f / 160.f);
    const float rstd = rsqrtf(var + 1e-5f);
    hout[hb + c0]     = f2b(d0 * rstd * gamma_[c0]     + beta_[c0]);
    hout[hb + c0 + 1] = f2b(d1 * rstd * gamma_[c0 + 1] + beta_[c0 + 1]);
    if (l < 32) hout[hb + c2] = f2b(d2 * rstd * gamma_[c2] + beta_[c2]);
  } else {
    hout[hb + c0]     = f2b(v0);
    hout[hb + c0 + 1] = f2b(v1);
    if (l < 32) hout[hb + c2] = f2b(v2);
  }
}

extern "C" void kernel_launch(void* const* d_in, const int* in_sizes, int n_in,
                              void* d_out, int out_size, void* d_ws, size_t ws_size,
                              hipStream_t stream)
{
  const float* x     = (const float*)d_in[0];
  const int*   ei    = (const int*)d_in[1];
  const float* W1    = (const float*)d_in[2];
  const float* att1s = (const float*)d_in[3];
  const float* att1d = (const float*)d_in[4];
  const float* b1    = (const float*)d_in[5];
  const float* g1    = (const float*)d_in[6];
  const float* be1   = (const float*)d_in[7];
  const float* W2    = (const float*)d_in[8];
  const float* att2s = (const float*)d_in[9];
  const float* att2d = (const float*)d_in[10];
  const float* b2    = (const float*)d_in[11];
  const float* Wm    = (const float*)d_in[12];
  const float* bm    = (const float*)d_in[13];

  float* out    = (float*)d_out;                      // [N,160]
  float* alpha1 = out + (long)N_NODES * HID;          // [E,5]
  float* alpha2 = alpha1 + (long)E_TOT * 5;           // [E,5]

  char* p = (char*)d_ws;
  auto alloc = [&](size_t bytes) { void* r = (void*)p; p += (bytes + 255) & ~(size_t)255; return r; };
  unsigned short* hb16 = (unsigned short*)alloc((size_t)N_NODES * HID * 2);
  unsigned short* xlh  = (unsigned short*)alloc((size_t)N_NODES * XSTR * 2);
  float* ad_  = (float*)alloc((size_t)N_NODES * 5 * 4);
  int* deg    = (int*)alloc((size_t)N_NODES * 4);
  int* fillc  = (int*)alloc((size_t)N_NODES * 4);
  int* off    = (int*)alloc((size_t)(N_NODES + 1) * 4);
  int* csrS   = (int*)alloc((size_t)E_TOT * 4);
  int* csrE   = (int*)alloc((size_t)E_TOT * 4);
  int* flag   = (int*)alloc(256);
  unsigned short* Bt1 = (unsigned short*)alloc((size_t)HID * 512 * 2);
  unsigned short* Bt2 = (unsigned short*)alloc((size_t)HID * 192 * 2);
  unsigned short* Btm = (unsigned short*)alloc((size_t)HID * 192 * 2);

  hipMemsetAsync(deg, 0, (size_t)N_NODES * 4, stream);
  hipMemsetAsync(fillc, 0, (size_t)N_NODES * 4, stream);

  detect_kernel<<<1, 64, 0, stream>>>(ei, flag);
  const int EB = (E_TOT + 255) / 256;
  count_kernel<<<EB, 256, 0, stream>>>(ei, flag, deg);
  scan_kernel<<<1, 1024, 0, stream>>>(deg, off);
  fill_kernel<<<EB, 256, 0, stream>>>(ei, flag, off, fillc, csrS, csrE);

  convert_all<<<(HID * 512 + 255) / 256, 256, 0, stream>>>(W1, W2, Wm, Bt1, Bt2, Btm);

  const int GB = (N_NODES + 31) / 32;

  // layer 1: bf16 pipelined LDS-GEMM (BM=32, col-split waves) + att dots
  gemm_lds<float, F_IN_K, 512, 64, 2><<<GB, 256, 0, stream>>>(x, Bt1, nullptr, xlh, nullptr, att1s, att1d, ad_);
  node_kernel<1><<<N_NODES / 4, 256, 0, stream>>>(off, csrS, csrE, xlh, ad_, alpha1, b1, g1, be1, hb16);

  // layer 2
  gemm_lds<unsigned short, HID, 192, 64, 2><<<GB, 256, 0, stream>>>(hb16, Bt2, nullptr, xlh, nullptr, att2s, att2d, ad_);
  node_kernel<0><<<N_NODES / 4, 256, 0, stream>>>(off, csrS, csrE, xlh, ad_, alpha2, b2, nullptr, nullptr, hb16);

  // final MLP: out = leaky(h2 @ Wm + bm)
  gemm_lds<unsigned short, HID, 192, 64, 1><<<GB, 256, 0, stream>>>(hb16, Btm, out, nullptr, bm, nullptr, nullptr, nullptr);
}

// Round 15
// 409.482 us; speedup vs baseline: 1.0031x; 1.0031x over previous
//
#include <hip/hip_runtime.h>

#define N_NODES 50000
#define E_RAW_N 800000
#define E_TOT   850000
#define F_IN_K  500
#define HID     160
#define XSTR    192   // packed row: 160 bf16 cols + 5 f32 a_s; 384B = 3 L2 lines

using short8 = __attribute__((ext_vector_type(8))) short;
using f32x4  = __attribute__((ext_vector_type(4))) float;

__device__ __forceinline__ float b2f(unsigned short u) {
  union { unsigned int i; float f; } v; v.i = ((unsigned int)u) << 16; return v.f;
}
__device__ __forceinline__ unsigned short f2b(float f) {
  union { float f; unsigned int i; } v; v.f = f;
  unsigned int i = v.i;
  unsigned int lsb = (i >> 16) & 1u;
  i += 0x7fffu + lsb;
  return (unsigned short)(i >> 16);
}

__device__ __forceinline__ float wsum(float x) {
  #pragma unroll
  for (int o = 32; o; o >>= 1) x += __shfl_xor(x, o, 64);
  return x;
}
__device__ __forceinline__ float wmax(float x) {
  #pragma unroll
  for (int o = 32; o; o >>= 1) x = fmaxf(x, __shfl_xor(x, o, 64));
  return x;
}
__device__ __forceinline__ float lrelu2(float x) { return x > 0.f ? x : 0.2f * x; }

// ---------------- edge dtype detection (int64 vs int32 hedge) ----------------
__global__ void detect_kernel(const int* __restrict__ ei, int* __restrict__ flag) {
  if (threadIdx.x == 0 && blockIdx.x == 0) {
    int allz = 1;
    for (int i = 1; i < 128; i += 2) if (ei[i] != 0) { allz = 0; break; }
    *flag = allz;  // 1 => int64 layout
  }
}
__device__ __forceinline__ int edge_src(const int* ei, int wide, int e) {
  return wide ? ei[2 * e] : ei[e];
}
__device__ __forceinline__ int edge_dst(const int* ei, int wide, int e) {
  return wide ? ei[2 * (E_RAW_N + e)] : ei[E_RAW_N + e];
}

// ------- weight pre-convert (all 3 weights in one launch): f32 -> bf16 -------
__global__ __launch_bounds__(256) void convert_all(
    const float* __restrict__ W1, const float* __restrict__ W2, const float* __restrict__ Wm,
    unsigned short* __restrict__ Bt1, unsigned short* __restrict__ Bt2,
    unsigned short* __restrict__ Btm)
{
  const int i = blockIdx.x * 256 + threadIdx.x;
  if (i < HID * 512) {
    const int c = i / 512, k = i % 512;
    Bt1[i] = f2b((k < F_IN_K) ? W1[(long)k * HID + c] : 0.f);
  }
  if (i < HID * 192) {
    const int c = i / 192, k = i % 192;
    Bt2[i] = f2b((k < HID) ? W2[(long)k * HID + c] : 0.f);
    Btm[i] = f2b((k < HID) ? Wm[(long)k * HID + c] : 0.f);
  }
}

// ---------------- GEMM: [M,160] = A[M,K] @ B, LDS-staged B, pipelined --------
// block = 2 waves (128 thr), BM=32; wave = 16 rows x 160 cols, 16x16x32 MFMA.
// AT=float: A converted to bf16 in-register. AT=ushort: direct short8 loads.
// MODE 1: +bias, leaky(0.01), C f32 (stride 160).
// MODE 2: packed row out (stride XSTR): bf16 cols + fused att-dot a_s; a_d arr.
template<typename AT, int K, int KPAD, int BK, int MODE>
__global__ __launch_bounds__(128) void gemm_lds(
    const AT* __restrict__ A, const unsigned short* __restrict__ Bt,
    float* __restrict__ C, unsigned short* __restrict__ Ch,
    const float* __restrict__ bias,
    const float* __restrict__ att_s, const float* __restrict__ att_d,
    float* __restrict__ a_d)
{
  constexpr bool AB16 = (sizeof(AT) == 2);
  constexpr int LSTR = BK + 8;
  constexpr int CHUNKS = KPAD / BK;
  constexpr int KSC = BK / 32;
  constexpr int ROWU = BK / 8;
  constexpr int UNITS = HID * ROWU;
  static_assert(UNITS % 128 == 0, "units must tile threads");
  constexpr int UPT = UNITS / 128;
  __shared__ __align__(16) unsigned short Bs[HID][LSTR];

  const int t = threadIdx.x;
  const int l = t & 63;
  const int w = t >> 6;
  const int m = l & 15;
  const int kgrp = (l >> 4) * 8;
  const int rbase = blockIdx.x * 32 + w * 16;
  const int arow = (rbase + m < N_NODES) ? rbase + m : N_NODES - 1;
  const AT* Arow = A + (long)arow * K;

  f32x4 acc[10];
  #pragma unroll
  for (int i = 0; i < 10; ++i) acc[i] = (f32x4){0.f, 0.f, 0.f, 0.f};

  short8 rb[UPT];
  float  arF[KSC][8], arF2[KSC][8];
  short8 arS[KSC], arS2[KSC];

  auto loadB = [&](int cc, short8* dst) {
    #pragma unroll
    for (int i = 0; i < UPT; ++i) {
      const int u = i * 128 + t;
      const int c = u / ROWU;
      const int k8 = u % ROWU;
      dst[i] = *(const short8*)(Bt + (long)c * KPAD + cc * BK + k8 * 8);
    }
  };
  auto loadA = [&](int cc, float aF[KSC][8], short8* aS) {
    #pragma unroll
    for (int ks = 0; ks < KSC; ++ks) {
      const int kb = cc * BK + ks * 32 + kgrp;
      if constexpr (AB16) {
        short8 v = (short8){0,0,0,0,0,0,0,0};
        if (kb + 8 <= K) v = *(const short8*)(Arow + kb);
        else if (kb < K) {
          #pragma unroll
          for (int j = 0; j < 8; ++j) v[j] = (kb + j < K) ? (short)Arow[kb + j] : (short)0;
        }
        aS[ks] = v;
      } else {
        if (kb + 8 <= K) {
          const float4 a0 = *(const float4*)(Arow + kb);
          const float4 a1 = *(const float4*)(Arow + kb + 4);
          aF[ks][0]=a0.x; aF[ks][1]=a0.y; aF[ks][2]=a0.z; aF[ks][3]=a0.w;
          aF[ks][4]=a1.x; aF[ks][5]=a1.y; aF[ks][6]=a1.z; aF[ks][7]=a1.w;
        } else {
          #pragma unroll
          for (int j = 0; j < 8; ++j) aF[ks][j] = (kb + j < K) ? (float)Arow[kb + j] : 0.f;
        }
      }
    }
  };

  loadB(0, rb);
  loadA(0, arF, arS);

  for (int cc = 0; cc < CHUNKS; ++cc) {
    __syncthreads();
    #pragma unroll
    for (int i = 0; i < UPT; ++i) {
      const int u = i * 128 + t;
      const int c = u / ROWU;
      const int k8 = u % ROWU;
      *(short8*)&Bs[c][k8 * 8] = rb[i];
    }
    __syncthreads();
    if (cc + 1 < CHUNKS) {
      loadB(cc + 1, rb);
      loadA(cc + 1, arF2, arS2);
      __builtin_amdgcn_sched_barrier(0);
    }
    __builtin_amdgcn_s_setprio(1);
    #pragma unroll
    for (int ks = 0; ks < KSC; ++ks) {
      short8 ah;
      if constexpr (AB16) {
        ah = arS[ks];
      } else {
        #pragma unroll
        for (int j = 0; j < 8; ++j) ah[j] = (short)f2b(arF[ks][j]);
      }
      #pragma unroll
      for (int ct = 0; ct < 10; ++ct) {
        const short8 bh = *(const short8*)&Bs[ct * 16 + m][ks * 32 + kgrp];
        acc[ct] = __builtin_amdgcn_mfma_f32_16x16x32_bf16(ah, bh, acc[ct], 0, 0, 0);
      }
    }
    __builtin_amdgcn_s_setprio(0);
    if (cc + 1 < CHUNKS) {
      #pragma unroll
      for (int ks = 0; ks < KSC; ++ks) {
        if constexpr (AB16) arS[ks] = arS2[ks];
        else {
          #pragma unroll
          for (int j = 0; j < 8; ++j) arF[ks][j] = arF2[ks][j];
        }
      }
    }
  }

  const int crow0 = rbase + (l >> 4) * 4;

  if (MODE == 2) {
    // fused attention dots; a_s packed into row tail, a_d to its own array
    #pragma unroll
    for (int r = 0; r < 4; ++r) {
      float ps[5], pd[5];
      #pragma unroll
      for (int h = 0; h < 5; ++h) {
        float s = acc[2*h][r]     * att_s[(2*h) * 16 + m]
                + acc[2*h + 1][r] * att_s[(2*h + 1) * 16 + m];
        float d = acc[2*h][r]     * att_d[(2*h) * 16 + m]
                + acc[2*h + 1][r] * att_d[(2*h + 1) * 16 + m];
        #pragma unroll
        for (int o = 1; o < 16; o <<= 1) {
          s += __shfl_xor(s, o, 64);
          d += __shfl_xor(d, o, 64);
        }
        ps[h] = s; pd[h] = d;
      }
      const int crow = crow0 + r;
      if (crow < N_NODES && m < 5) {
        const float vs = m == 0 ? ps[0] : m == 1 ? ps[1] : m == 2 ? ps[2] : m == 3 ? ps[3] : ps[4];
        const float vd = m == 0 ? pd[0] : m == 1 ? pd[1] : m == 2 ? pd[2] : m == 3 ? pd[3] : pd[4];
        ((float*)(Ch + (long)crow * XSTR + 160))[m] = vs;
        a_d[crow * 5 + m] = vd;
      }
    }
  }

  #pragma unroll
  for (int r = 0; r < 4; ++r) {
    const int crow = crow0 + r;
    if (crow < N_NODES) {
      #pragma unroll
      for (int ct = 0; ct < 10; ++ct) {
        const int col = ct * 16 + m;
        float v = acc[ct][r];
        if (MODE == 1) { v += bias[col]; v = v > 0.f ? v : 0.01f * v; }
        if (MODE == 2) Ch[(long)crow * XSTR + col] = f2b(v);
        else           C[(long)crow * HID + col] = v;
      }
    }
  }
}

// ---------------- CSR build ---------------------------------------------------
__global__ __launch_bounds__(256) void count_kernel(const int* __restrict__ ei,
    const int* __restrict__ flag, int* __restrict__ deg) {
  const int e = blockIdx.x * 256 + threadIdx.x;
  if (e >= E_TOT) return;
  const int wide = *flag;
  const int d = (e < E_RAW_N) ? edge_dst(ei, wide, e) : (e - E_RAW_N);
  atomicAdd(&deg[d], 1);
}

#define SCAN_CHUNK 49  // 1024*49 = 50176 >= 50000
__global__ __launch_bounds__(1024) void scan_kernel(const int* __restrict__ deg, int* __restrict__ off) {
  __shared__ int wtot[16];
  const int t = threadIdx.x;
  const int lane = t & 63, wid = t >> 6;
  const int base = t * SCAN_CHUNK;
  int local[SCAN_CHUNK];
  int sum = 0;
  #pragma unroll
  for (int i = 0; i < SCAN_CHUNK; ++i) {
    const int idx = base + i;
    const int v = (idx < N_NODES) ? deg[idx] : 0;
    local[i] = sum;
    sum += v;
  }
  int inc = sum;
  #pragma unroll
  for (int o = 1; o < 64; o <<= 1) {
    const int y = __shfl_up(inc, o, 64);
    if (lane >= o) inc += y;
  }
  if (lane == 63) wtot[wid] = inc;
  __syncthreads();
  if (wid == 0 && lane < 16) {
    const int v = wtot[lane];
    int inc2 = v;
    #pragma unroll
    for (int o = 1; o < 16; o <<= 1) {
      const int y = __shfl_up(inc2, o, 64);
      if (lane >= o) inc2 += y;
    }
    wtot[lane] = inc2 - v;  // exclusive
  }
  __syncthreads();
  const int pre = wtot[wid] + (inc - sum);
  #pragma unroll
  for (int i = 0; i < SCAN_CHUNK; ++i) {
    const int idx = base + i;
    if (idx < N_NODES) off[idx] = pre + local[i];
  }
  if (t == 1023) off[N_NODES] = E_TOT;
}

__global__ __launch_bounds__(256) void fill_kernel(const int* __restrict__ ei,
    const int* __restrict__ flag, const int* __restrict__ off,
    int* __restrict__ fillc, int* __restrict__ csr_src, int* __restrict__ csr_eid) {
  const int e = blockIdx.x * 256 + threadIdx.x;
  if (e >= E_TOT) return;
  const int wide = *flag;
  int s, d;
  if (e < E_RAW_N) { s = edge_src(ei, wide, e); d = edge_dst(ei, wide, e); }
  else { s = e - E_RAW_N; d = s; }
  const int p = off[d] + atomicAdd(&fillc[d], 1);
  csr_src[p] = s;
  csr_eid[p] = e;
}

// ---------------- fused per-node segment-softmax + aggregation ---------------
// xlh rows packed (XSTR=192, 384B = 3 cache lines): bf16 cols [0..160) +
// a_s f32 at [160..170). Fast path (deg<=64): register softmax (no max pass);
// edge table in LDS; unroll-8 gather.
template<int DO_LN>
__global__ __launch_bounds__(256) void node_kernel(
    const int* __restrict__ off_, const int* __restrict__ csr_src, const int* __restrict__ csr_eid,
    const unsigned short* __restrict__ xlh,
    const float* __restrict__ a_d,
    float* __restrict__ alpha_out,
    const float* __restrict__ bias,
    const float* __restrict__ gamma_, const float* __restrict__ beta_,
    unsigned short* __restrict__ hout)
{
  __shared__ int   srcS[4][64];
  __shared__ float alS[4][64][6];

  const int w = threadIdx.x >> 6;
  const int l = threadIdx.x & 63;
  const int n = blockIdx.x * 4 + w;
  if (n >= N_NODES) return;
  const int off = off_[n];
  const int deg = off_[n + 1] - off;

  const float ad0 = a_d[n*5+0], ad1 = a_d[n*5+1], ad2 = a_d[n*5+2], ad3 = a_d[n*5+3], ad4 = a_d[n*5+4];
  const int hA = l >> 4;  // head for cols 2l, 2l+1
  float accx = 0.f, accy = 0.f, accz = 0.f;

  if (deg <= 64) {
    // ---- register softmax (no max pass): one lane per edge ----
    int src = 0, eid = 0;
    float e0 = 0.f, e1 = 0.f, e2 = 0.f, e3 = 0.f, e4 = 0.f;
    if (l < deg) {
      src = csr_src[off + l];
      eid = csr_eid[off + l];
      const float* ap = (const float*)(xlh + (unsigned)src * XSTR + 160);
      e0 = __expf(lrelu2(ap[0] + ad0));
      e1 = __expf(lrelu2(ap[1] + ad1));
      e2 = __expf(lrelu2(ap[2] + ad2));
      e3 = __expf(lrelu2(ap[3] + ad3));
      e4 = __expf(lrelu2(ap[4] + ad4));
    }
    const float i0 = 1.f / (wsum(e0) + 1e-16f), i1 = 1.f / (wsum(e1) + 1e-16f),
                i2 = 1.f / (wsum(e2) + 1e-16f), i3 = 1.f / (wsum(e3) + 1e-16f),
                i4 = 1.f / (wsum(e4) + 1e-16f);
    const float a0 = e0 * i0, a1 = e1 * i1, a2 = e2 * i2, a3 = e3 * i3, a4 = e4 * i4;
    if (l < deg) {
      float* aw = alpha_out + (long)eid * 5;
      aw[0] = a0; aw[1] = a1; aw[2] = a2; aw[3] = a3; aw[4] = a4;
    }
    srcS[w][l] = src;
    alS[w][l][0] = a0; alS[w][l][1] = a1; alS[w][l][2] = a2;
    alS[w][l][3] = a3; alS[w][l][4] = a4;

    const int degR = (deg + 7) & ~7;
    const unsigned cx = 2 * l, cz = 128 + l;
    for (int s0 = 0; s0 < degR; s0 += 8) {
      int sr[8]; float aA[8], aB[8];
      #pragma unroll
      for (int j = 0; j < 8; ++j) {
        sr[j] = srcS[w][s0 + j];
        aA[j] = alS[w][s0 + j][hA];
        aB[j] = alS[w][s0 + j][4];
      }
      ushort2 u2[8]; unsigned short z[8];
      #pragma unroll
      for (int j = 0; j < 8; ++j) {
        const unsigned xb = (unsigned)sr[j] * XSTR;
        u2[j] = *(const ushort2*)(xlh + xb + cx);
        if (l < 32) z[j] = xlh[xb + cz];
      }
      #pragma unroll
      for (int j = 0; j < 8; ++j) {
        accx += b2f(u2[j].x) * aA[j];
        accy += b2f(u2[j].y) * aA[j];
        if (l < 32) accz += b2f(z[j]) * aB[j];
      }
    }
  } else {
    // ---- slow path (rare): 3-pass over segment ----
    float m0 = -1e30f, m1 = -1e30f, m2 = -1e30f, m3 = -1e30f, m4 = -1e30f;
    for (int s = l; s < deg; s += 64) {
      const float* ap = (const float*)(xlh + (unsigned)csr_src[off + s] * XSTR + 160);
      m0 = fmaxf(m0, lrelu2(ap[0] + ad0));
      m1 = fmaxf(m1, lrelu2(ap[1] + ad1));
      m2 = fmaxf(m2, lrelu2(ap[2] + ad2));
      m3 = fmaxf(m3, lrelu2(ap[3] + ad3));
      m4 = fmaxf(m4, lrelu2(ap[4] + ad4));
    }
    m0 = wmax(m0); m1 = wmax(m1); m2 = wmax(m2); m3 = wmax(m3); m4 = wmax(m4);
    float s0 = 0.f, s1 = 0.f, s2 = 0.f, s3 = 0.f, s4 = 0.f;
    for (int s = l; s < deg; s += 64) {
      const float* ap = (const float*)(xlh + (unsigned)csr_src[off + s] * XSTR + 160);
      s0 += __expf(lrelu2(ap[0] + ad0) - m0);
      s1 += __expf(lrelu2(ap[1] + ad1) - m1);
      s2 += __expf(lrelu2(ap[2] + ad2) - m2);
      s3 += __expf(lrelu2(ap[3] + ad3) - m3);
      s4 += __expf(lrelu2(ap[4] + ad4) - m4);
    }
    const float i0 = 1.f / (wsum(s0) + 1e-16f), i1 = 1.f / (wsum(s1) + 1e-16f),
                i2 = 1.f / (wsum(s2) + 1e-16f), i3 = 1.f / (wsum(s3) + 1e-16f),
                i4 = 1.f / (wsum(s4) + 1e-16f);
    const float adA = hA == 0 ? ad0 : hA == 1 ? ad1 : hA == 2 ? ad2 : ad3;
    const float mA  = hA == 0 ? m0  : hA == 1 ? m1  : hA == 2 ? m2  : m3;
    const float iA  = hA == 0 ? i0  : hA == 1 ? i1  : hA == 2 ? i2  : i3;
    float adw = 0.f, mw = 0.f, iw = 0.f;
    if (l < 5) {
      adw = l == 0 ? ad0 : l == 1 ? ad1 : l == 2 ? ad2 : l == 3 ? ad3 : ad4;
      mw  = l == 0 ? m0  : l == 1 ? m1  : l == 2 ? m2  : l == 3 ? m3  : m4;
      iw  = l == 0 ? i0  : l == 1 ? i1  : l == 2 ? i2  : l == 3 ? i3  : i4;
    }
    for (int s = 0; s < deg; ++s) {
      const int p = off + s;
      const int srcs = csr_src[p];
      const unsigned xb = (unsigned)srcs * XSTR;
      const float* ap = (const float*)(xlh + xb + 160);
      const float aA = __expf(lrelu2(ap[hA] + adA) - mA) * iA;
      const ushort2 u2 = *(const ushort2*)(xlh + xb + 2 * l);
      accx += b2f(u2.x) * aA;
      accy += b2f(u2.y) * aA;
      if (l < 32) {
        const float aC = __expf(lrelu2(ap[4] + ad4) - m4) * i4;
        accz += b2f(xlh[xb + 128 + l]) * aC;
      }
      if (l < 5) {
        alpha_out[(long)csr_eid[p] * 5 + l] = __expf(lrelu2(ap[l] + adw) - mw) * iw;
      }
    }
  }

  // epilogue (bf16 store)
  const int c0 = 2 * l, c2 = 128 + l;
  float v0 = accx + bias[c0];     v0 = v0 > 0.f ? v0 : 0.01f * v0;
  float v1 = accy + bias[c0 + 1]; v1 = v1 > 0.f ? v1 : 0.01f * v1;
  float v2 = 0.f;
  if (l < 32) { v2 = accz + bias[c2]; v2 = v2 > 0.f ? v2 : 0.01f * v2; }

  const long hb = (long)n * HID;
  if (DO_LN) {
    const float tot = wsum(v0 + v1 + v2);
    const float mean = tot * (1.f / 160.f);
    const float d0 = v0 - mean, d1 = v1 - mean;
    float sq = d0 * d0 + d1 * d1;
    float d2 = 0.f;
    if (l < 32) { d2 = v2 - mean; sq += d2 * d2; }
    const float var = wsum(sq) * (1.f / 160.f);
    const float rstd = rsqrtf(var + 1e-5f);
    hout[hb + c0]     = f2b(d0 * rstd * gamma_[c0]     + beta_[c0]);
    hout[hb + c0 + 1] = f2b(d1 * rstd * gamma_[c0 + 1] + beta_[c0 + 1]);
    if (l < 32) hout[hb + c2] = f2b(d2 * rstd * gamma_[c2] + beta_[c2]);
  } else {
    hout[hb + c0]     = f2b(v0);
    hout[hb + c0 + 1] = f2b(v1);
    if (l < 32) hout[hb + c2] = f2b(v2);
  }
}

extern "C" void kernel_launch(void* const* d_in, const int* in_sizes, int n_in,
                              void* d_out, int out_size, void* d_ws, size_t ws_size,
                              hipStream_t stream)
{
  const float* x     = (const float*)d_in[0];
  const int*   ei    = (const int*)d_in[1];
  const float* W1    = (const float*)d_in[2];
  const float* att1s = (const float*)d_in[3];
  const float* att1d = (const float*)d_in[4];
  const float* b1    = (const float*)d_in[5];
  const float* g1    = (const float*)d_in[6];
  const float* be1   = (const float*)d_in[7];
  const float* W2    = (const float*)d_in[8];
  const float* att2s = (const float*)d_in[9];
  const float* att2d = (const float*)d_in[10];
  const float* b2    = (const float*)d_in[11];
  const float* Wm    = (const float*)d_in[12];
  const float* bm    = (const float*)d_in[13];

  float* out    = (float*)d_out;                      // [N,160]
  float* alpha1 = out + (long)N_NODES * HID;          // [E,5]
  float* alpha2 = alpha1 + (long)E_TOT * 5;           // [E,5]

  char* p = (char*)d_ws;
  auto alloc = [&](size_t bytes) { void* r = (void*)p; p += (bytes + 255) & ~(size_t)255; return r; };
  unsigned short* hb16 = (unsigned short*)alloc((size_t)N_NODES * HID * 2);
  unsigned short* xlh  = (unsigned short*)alloc((size_t)N_NODES * XSTR * 2);
  float* ad_  = (float*)alloc((size_t)N_NODES * 5 * 4);
  int* deg    = (int*)alloc((size_t)N_NODES * 4);
  int* fillc  = (int*)alloc((size_t)N_NODES * 4);
  int* off    = (int*)alloc((size_t)(N_NODES + 1) * 4);
  int* csrS   = (int*)alloc((size_t)E_TOT * 4);
  int* csrE   = (int*)alloc((size_t)E_TOT * 4);
  int* flag   = (int*)alloc(256);
  unsigned short* Bt1 = (unsigned short*)alloc((size_t)HID * 512 * 2);
  unsigned short* Bt2 = (unsigned short*)alloc((size_t)HID * 192 * 2);
  unsigned short* Btm = (unsigned short*)alloc((size_t)HID * 192 * 2);

  hipMemsetAsync(deg, 0, (size_t)N_NODES * 4, stream);
  hipMemsetAsync(fillc, 0, (size_t)N_NODES * 4, stream);

  detect_kernel<<<1, 64, 0, stream>>>(ei, flag);
  const int EB = (E_TOT + 255) / 256;
  count_kernel<<<EB, 256, 0, stream>>>(ei, flag, deg);
  scan_kernel<<<1, 1024, 0, stream>>>(deg, off);
  fill_kernel<<<EB, 256, 0, stream>>>(ei, flag, off, fillc, csrS, csrE);

  convert_all<<<(HID * 512 + 255) / 256, 256, 0, stream>>>(W1, W2, Wm, Bt1, Bt2, Btm);

  const int GB = (N_NODES + 31) / 32;

  // layer 1: bf16 pipelined LDS-GEMM (BM=32, BK=32 for occupancy) + att dots
  gemm_lds<float, F_IN_K, 512, 32, 2><<<GB, 128, 0, stream>>>(x, Bt1, nullptr, xlh, nullptr, att1s, att1d, ad_);
  node_kernel<1><<<N_NODES / 4, 256, 0, stream>>>(off, csrS, csrE, xlh, ad_, alpha1, b1, g1, be1, hb16);

  // layer 2
  gemm_lds<unsigned short, HID, 192, 64, 2><<<GB, 128, 0, stream>>>(hb16, Bt2, nullptr, xlh, nullptr, att2s, att2d, ad_);
  node_kernel<0><<<N_NODES / 4, 256, 0, stream>>>(off, csrS, csrE, xlh, ad_, alpha2, b2, nullptr, nullptr, hb16);

  // final MLP: out = leaky(h2 @ Wm + bm)
  gemm_lds<unsigned short, HID, 192, 64, 1><<<GB, 128, 0, stream>>>(hb16, Btm, out, nullptr, bm, nullptr, nullptr, nullptr);
}

// Round 16
// 399.524 us; speedup vs baseline: 1.0281x; 1.0249x over previous
//
#include <hip/hip_runtime.h>

#define N_NODES 50000
#define E_RAW_N 800000
#define E_TOT   850000
#define F_IN_K  500
#define HID     160
#define XSTR    192   // packed row: 160 bf16 cols + 5 f32 a_s; 384B = 3 L2 lines

using short8 = __attribute__((ext_vector_type(8))) short;
using f32x4  = __attribute__((ext_vector_type(4))) float;

__device__ __forceinline__ float b2f(unsigned short u) {
  union { unsigned int i; float f; } v; v.i = ((unsigned int)u) << 16; return v.f;
}
__device__ __forceinline__ unsigned short f2b(float f) {
  union { float f; unsigned int i; } v; v.f = f;
  unsigned int i = v.i;
  unsigned int lsb = (i >> 16) & 1u;
  i += 0x7fffu + lsb;
  return (unsigned short)(i >> 16);
}

__device__ __forceinline__ float wsum(float x) {
  #pragma unroll
  for (int o = 32; o; o >>= 1) x += __shfl_xor(x, o, 64);
  return x;
}
__device__ __forceinline__ float wmax(float x) {
  #pragma unroll
  for (int o = 32; o; o >>= 1) x = fmaxf(x, __shfl_xor(x, o, 64));
  return x;
}
__device__ __forceinline__ float lrelu2(float x) { return x > 0.f ? x : 0.2f * x; }

// ---------------- edge dtype detection (int64 vs int32 hedge) ----------------
__global__ void detect_kernel(const int* __restrict__ ei, int* __restrict__ flag) {
  if (threadIdx.x == 0 && blockIdx.x == 0) {
    int allz = 1;
    for (int i = 1; i < 128; i += 2) if (ei[i] != 0) { allz = 0; break; }
    *flag = allz;  // 1 => int64 layout
  }
}
__device__ __forceinline__ int edge_src(const int* ei, int wide, int e) {
  return wide ? ei[2 * e] : ei[e];
}
__device__ __forceinline__ int edge_dst(const int* ei, int wide, int e) {
  return wide ? ei[2 * (E_RAW_N + e)] : ei[E_RAW_N + e];
}

// ------- weight pre-convert (all 3 weights in one launch): f32 -> bf16 -------
__global__ __launch_bounds__(256) void convert_all(
    const float* __restrict__ W1, const float* __restrict__ W2, const float* __restrict__ Wm,
    unsigned short* __restrict__ Bt1, unsigned short* __restrict__ Bt2,
    unsigned short* __restrict__ Btm)
{
  const int i = blockIdx.x * 256 + threadIdx.x;
  if (i < HID * 512) {
    const int c = i / 512, k = i % 512;
    Bt1[i] = f2b((k < F_IN_K) ? W1[(long)k * HID + c] : 0.f);
  }
  if (i < HID * 192) {
    const int c = i / 192, k = i % 192;
    Bt2[i] = f2b((k < HID) ? W2[(long)k * HID + c] : 0.f);
    Btm[i] = f2b((k < HID) ? Wm[(long)k * HID + c] : 0.f);
  }
}

// ---------------- GEMM: [M,160] = A[M,K] @ B, LDS-staged B, pipelined --------
// block = 2 waves (128 thr), BM=32; wave = 16 rows x 160 cols, 16x16x32 MFMA.
// AT=float: A converted to bf16 in-register. AT=ushort: direct short8 loads.
// MODE 1: +bias, leaky(0.01), C f32 (stride 160).
// MODE 2: packed row out (stride XSTR): bf16 cols + fused att-dot a_s; a_d arr.
template<typename AT, int K, int KPAD, int BK, int MODE>
__global__ __launch_bounds__(128) void gemm_lds(
    const AT* __restrict__ A, const unsigned short* __restrict__ Bt,
    float* __restrict__ C, unsigned short* __restrict__ Ch,
    const float* __restrict__ bias,
    const float* __restrict__ att_s, const float* __restrict__ att_d,
    float* __restrict__ a_d)
{
  constexpr bool AB16 = (sizeof(AT) == 2);
  constexpr int LSTR = BK + 8;
  constexpr int CHUNKS = KPAD / BK;
  constexpr int KSC = BK / 32;
  constexpr int ROWU = BK / 8;
  constexpr int UNITS = HID * ROWU;
  static_assert(UNITS % 128 == 0, "units must tile threads");
  constexpr int UPT = UNITS / 128;
  __shared__ __align__(16) unsigned short Bs[HID][LSTR];

  const int t = threadIdx.x;
  const int l = t & 63;
  const int w = t >> 6;
  const int m = l & 15;
  const int kgrp = (l >> 4) * 8;
  const int rbase = blockIdx.x * 32 + w * 16;
  const int arow = (rbase + m < N_NODES) ? rbase + m : N_NODES - 1;
  const AT* Arow = A + (long)arow * K;

  f32x4 acc[10];
  #pragma unroll
  for (int i = 0; i < 10; ++i) acc[i] = (f32x4){0.f, 0.f, 0.f, 0.f};

  short8 rb[UPT];
  float  arF[KSC][8], arF2[KSC][8];
  short8 arS[KSC], arS2[KSC];

  auto loadB = [&](int cc, short8* dst) {
    #pragma unroll
    for (int i = 0; i < UPT; ++i) {
      const int u = i * 128 + t;
      const int c = u / ROWU;
      const int k8 = u % ROWU;
      dst[i] = *(const short8*)(Bt + (long)c * KPAD + cc * BK + k8 * 8);
    }
  };
  auto loadA = [&](int cc, float aF[KSC][8], short8* aS) {
    #pragma unroll
    for (int ks = 0; ks < KSC; ++ks) {
      const int kb = cc * BK + ks * 32 + kgrp;
      if constexpr (AB16) {
        short8 v = (short8){0,0,0,0,0,0,0,0};
        if (kb + 8 <= K) v = *(const short8*)(Arow + kb);
        else if (kb < K) {
          #pragma unroll
          for (int j = 0; j < 8; ++j) v[j] = (kb + j < K) ? (short)Arow[kb + j] : (short)0;
        }
        aS[ks] = v;
      } else {
        if (kb + 8 <= K) {
          const float4 a0 = *(const float4*)(Arow + kb);
          const float4 a1 = *(const float4*)(Arow + kb + 4);
          aF[ks][0]=a0.x; aF[ks][1]=a0.y; aF[ks][2]=a0.z; aF[ks][3]=a0.w;
          aF[ks][4]=a1.x; aF[ks][5]=a1.y; aF[ks][6]=a1.z; aF[ks][7]=a1.w;
        } else {
          #pragma unroll
          for (int j = 0; j < 8; ++j) aF[ks][j] = (kb + j < K) ? (float)Arow[kb + j] : 0.f;
        }
      }
    }
  };

  loadB(0, rb);
  loadA(0, arF, arS);

  for (int cc = 0; cc < CHUNKS; ++cc) {
    __syncthreads();
    #pragma unroll
    for (int i = 0; i < UPT; ++i) {
      const int u = i * 128 + t;
      const int c = u / ROWU;
      const int k8 = u % ROWU;
      *(short8*)&Bs[c][k8 * 8] = rb[i];
    }
    __syncthreads();
    if (cc + 1 < CHUNKS) {
      loadB(cc + 1, rb);
      loadA(cc + 1, arF2, arS2);
      __builtin_amdgcn_sched_barrier(0);
    }
    __builtin_amdgcn_s_setprio(1);
    #pragma unroll
    for (int ks = 0; ks < KSC; ++ks) {
      short8 ah;
      if constexpr (AB16) {
        ah = arS[ks];
      } else {
        #pragma unroll
        for (int j = 0; j < 8; ++j) ah[j] = (short)f2b(arF[ks][j]);
      }
      #pragma unroll
      for (int ct = 0; ct < 10; ++ct) {
        const short8 bh = *(const short8*)&Bs[ct * 16 + m][ks * 32 + kgrp];
        acc[ct] = __builtin_amdgcn_mfma_f32_16x16x32_bf16(ah, bh, acc[ct], 0, 0, 0);
      }
    }
    __builtin_amdgcn_s_setprio(0);
    if (cc + 1 < CHUNKS) {
      #pragma unroll
      for (int ks = 0; ks < KSC; ++ks) {
        if constexpr (AB16) arS[ks] = arS2[ks];
        else {
          #pragma unroll
          for (int j = 0; j < 8; ++j) arF[ks][j] = arF2[ks][j];
        }
      }
    }
  }

  const int crow0 = rbase + (l >> 4) * 4;

  if (MODE == 2) {
    // fused attention dots; a_s packed into row tail, a_d to its own array
    #pragma unroll
    for (int r = 0; r < 4; ++r) {
      float ps[5], pd[5];
      #pragma unroll
      for (int h = 0; h < 5; ++h) {
        float s = acc[2*h][r]     * att_s[(2*h) * 16 + m]
                + acc[2*h + 1][r] * att_s[(2*h + 1) * 16 + m];
        float d = acc[2*h][r]     * att_d[(2*h) * 16 + m]
                + acc[2*h + 1][r] * att_d[(2*h + 1) * 16 + m];
        #pragma unroll
        for (int o = 1; o < 16; o <<= 1) {
          s += __shfl_xor(s, o, 64);
          d += __shfl_xor(d, o, 64);
        }
        ps[h] = s; pd[h] = d;
      }
      const int crow = crow0 + r;
      if (crow < N_NODES && m < 5) {
        const float vs = m == 0 ? ps[0] : m == 1 ? ps[1] : m == 2 ? ps[2] : m == 3 ? ps[3] : ps[4];
        const float vd = m == 0 ? pd[0] : m == 1 ? pd[1] : m == 2 ? pd[2] : m == 3 ? pd[3] : pd[4];
        ((float*)(Ch + (long)crow * XSTR + 160))[m] = vs;
        a_d[crow * 5 + m] = vd;
      }
    }
  }

  #pragma unroll
  for (int r = 0; r < 4; ++r) {
    const int crow = crow0 + r;
    if (crow < N_NODES) {
      #pragma unroll
      for (int ct = 0; ct < 10; ++ct) {
        const int col = ct * 16 + m;
        float v = acc[ct][r];
        if (MODE == 1) { v += bias[col]; v = v > 0.f ? v : 0.01f * v; }
        if (MODE == 2) Ch[(long)crow * XSTR + col] = f2b(v);
        else           C[(long)crow * HID + col] = v;
      }
    }
  }
}

// ---------------- CSR build ---------------------------------------------------
__global__ __launch_bounds__(256) void count_kernel(const int* __restrict__ ei,
    const int* __restrict__ flag, int* __restrict__ deg) {
  const int e = blockIdx.x * 256 + threadIdx.x;
  if (e >= E_TOT) return;
  const int wide = *flag;
  const int d = (e < E_RAW_N) ? edge_dst(ei, wide, e) : (e - E_RAW_N);
  atomicAdd(&deg[d], 1);
}

#define SCAN_CHUNK 49  // 1024*49 = 50176 >= 50000
__global__ __launch_bounds__(1024) void scan_kernel(const int* __restrict__ deg, int* __restrict__ off) {
  __shared__ int wtot[16];
  const int t = threadIdx.x;
  const int lane = t & 63, wid = t >> 6;
  const int base = t * SCAN_CHUNK;
  int local[SCAN_CHUNK];
  int sum = 0;
  #pragma unroll
  for (int i = 0; i < SCAN_CHUNK; ++i) {
    const int idx = base + i;
    const int v = (idx < N_NODES) ? deg[idx] : 0;
    local[i] = sum;
    sum += v;
  }
  int inc = sum;
  #pragma unroll
  for (int o = 1; o < 64; o <<= 1) {
    const int y = __shfl_up(inc, o, 64);
    if (lane >= o) inc += y;
  }
  if (lane == 63) wtot[wid] = inc;
  __syncthreads();
  if (wid == 0 && lane < 16) {
    const int v = wtot[lane];
    int inc2 = v;
    #pragma unroll
    for (int o = 1; o < 16; o <<= 1) {
      const int y = __shfl_up(inc2, o, 64);
      if (lane >= o) inc2 += y;
    }
    wtot[lane] = inc2 - v;  // exclusive
  }
  __syncthreads();
  const int pre = wtot[wid] + (inc - sum);
  #pragma unroll
  for (int i = 0; i < SCAN_CHUNK; ++i) {
    const int idx = base + i;
    if (idx < N_NODES) off[idx] = pre + local[i];
  }
  if (t == 1023) off[N_NODES] = E_TOT;
}

__global__ __launch_bounds__(256) void fill_kernel(const int* __restrict__ ei,
    const int* __restrict__ flag, const int* __restrict__ off,
    int* __restrict__ fillc, int* __restrict__ csr_src, int* __restrict__ csr_eid) {
  const int e = blockIdx.x * 256 + threadIdx.x;
  if (e >= E_TOT) return;
  const int wide = *flag;
  int s, d;
  if (e < E_RAW_N) { s = edge_src(ei, wide, e); d = edge_dst(ei, wide, e); }
  else { s = e - E_RAW_N; d = s; }
  const int p = off[d] + atomicAdd(&fillc[d], 1);
  csr_src[p] = s;
  csr_eid[p] = e;
}

// ---------------- fused per-node segment-softmax + aggregation ---------------
// xlh rows packed (XSTR=192, 384B = 3 cache lines): bf16 cols [0..160) +
// a_s f32 at [160..170). Fast path (deg<=64): register softmax (no max pass);
// edge table in LDS; unroll-8 gather.
template<int DO_LN>
__global__ __launch_bounds__(256) void node_kernel(
    const int* __restrict__ off_, const int* __restrict__ csr_src, const int* __restrict__ csr_eid,
    const unsigned short* __restrict__ xlh,
    const float* __restrict__ a_d,
    float* __restrict__ alpha_out,
    const float* __restrict__ bias,
    const float* __restrict__ gamma_, const float* __restrict__ beta_,
    unsigned short* __restrict__ hout)
{
  __shared__ int   srcS[4][64];
  __shared__ float alS[4][64][6];

  const int w = threadIdx.x >> 6;
  const int l = threadIdx.x & 63;
  const int n = blockIdx.x * 4 + w;
  if (n >= N_NODES) return;
  const int off = off_[n];
  const int deg = off_[n + 1] - off;

  const float ad0 = a_d[n*5+0], ad1 = a_d[n*5+1], ad2 = a_d[n*5+2], ad3 = a_d[n*5+3], ad4 = a_d[n*5+4];
  const int hA = l >> 4;  // head for cols 2l, 2l+1
  float accx = 0.f, accy = 0.f, accz = 0.f;

  if (deg <= 64) {
    // ---- register softmax (no max pass): one lane per edge ----
    int src = 0, eid = 0;
    float e0 = 0.f, e1 = 0.f, e2 = 0.f, e3 = 0.f, e4 = 0.f;
    if (l < deg) {
      src = csr_src[off + l];
      eid = csr_eid[off + l];
      const float* ap = (const float*)(xlh + (unsigned)src * XSTR + 160);
      e0 = __expf(lrelu2(ap[0] + ad0));
      e1 = __expf(lrelu2(ap[1] + ad1));
      e2 = __expf(lrelu2(ap[2] + ad2));
      e3 = __expf(lrelu2(ap[3] + ad3));
      e4 = __expf(lrelu2(ap[4] + ad4));
    }
    const float i0 = 1.f / (wsum(e0) + 1e-16f), i1 = 1.f / (wsum(e1) + 1e-16f),
                i2 = 1.f / (wsum(e2) + 1e-16f), i3 = 1.f / (wsum(e3) + 1e-16f),
                i4 = 1.f / (wsum(e4) + 1e-16f);
    const float a0 = e0 * i0, a1 = e1 * i1, a2 = e2 * i2, a3 = e3 * i3, a4 = e4 * i4;
    if (l < deg) {
      float* aw = alpha_out + (long)eid * 5;
      aw[0] = a0; aw[1] = a1; aw[2] = a2; aw[3] = a3; aw[4] = a4;
    }
    srcS[w][l] = src;
    alS[w][l][0] = a0; alS[w][l][1] = a1; alS[w][l][2] = a2;
    alS[w][l][3] = a3; alS[w][l][4] = a4;

    const int degR = (deg + 7) & ~7;
    const unsigned cx = 2 * l, cz = 128 + l;
    for (int s0 = 0; s0 < degR; s0 += 8) {
      int sr[8]; float aA[8], aB[8];
      #pragma unroll
      for (int j = 0; j < 8; ++j) {
        sr[j] = srcS[w][s0 + j];
        aA[j] = alS[w][s0 + j][hA];
        aB[j] = alS[w][s0 + j][4];
      }
      ushort2 u2[8]; unsigned short z[8];
      #pragma unroll
      for (int j = 0; j < 8; ++j) {
        const unsigned xb = (unsigned)sr[j] * XSTR;
        u2[j] = *(const ushort2*)(xlh + xb + cx);
        if (l < 32) z[j] = xlh[xb + cz];
      }
      #pragma unroll
      for (int j = 0; j < 8; ++j) {
        accx += b2f(u2[j].x) * aA[j];
        accy += b2f(u2[j].y) * aA[j];
        if (l < 32) accz += b2f(z[j]) * aB[j];
      }
    }
  } else {
    // ---- slow path (rare): 3-pass over segment ----
    float m0 = -1e30f, m1 = -1e30f, m2 = -1e30f, m3 = -1e30f, m4 = -1e30f;
    for (int s = l; s < deg; s += 64) {
      const float* ap = (const float*)(xlh + (unsigned)csr_src[off + s] * XSTR + 160);
      m0 = fmaxf(m0, lrelu2(ap[0] + ad0));
      m1 = fmaxf(m1, lrelu2(ap[1] + ad1));
      m2 = fmaxf(m2, lrelu2(ap[2] + ad2));
      m3 = fmaxf(m3, lrelu2(ap[3] + ad3));
      m4 = fmaxf(m4, lrelu2(ap[4] + ad4));
    }
    m0 = wmax(m0); m1 = wmax(m1); m2 = wmax(m2); m3 = wmax(m3); m4 = wmax(m4);
    float s0 = 0.f, s1 = 0.f, s2 = 0.f, s3 = 0.f, s4 = 0.f;
    for (int s = l; s < deg; s += 64) {
      const float* ap = (const float*)(xlh + (unsigned)csr_src[off + s] * XSTR + 160);
      s0 += __expf(lrelu2(ap[0] + ad0) - m0);
      s1 += __expf(lrelu2(ap[1] + ad1) - m1);
      s2 += __expf(lrelu2(ap[2] + ad2) - m2);
      s3 += __expf(lrelu2(ap[3] + ad3) - m3);
      s4 += __expf(lrelu2(ap[4] + ad4) - m4);
    }
    const float i0 = 1.f / (wsum(s0) + 1e-16f), i1 = 1.f / (wsum(s1) + 1e-16f),
                i2 = 1.f / (wsum(s2) + 1e-16f), i3 = 1.f / (wsum(s3) + 1e-16f),
                i4 = 1.f / (wsum(s4) + 1e-16f);
    const float adA = hA == 0 ? ad0 : hA == 1 ? ad1 : hA == 2 ? ad2 : ad3;
    const float mA  = hA == 0 ? m0  : hA == 1 ? m1  : hA == 2 ? m2  : m3;
    const float iA  = hA == 0 ? i0  : hA == 1 ? i1  : hA == 2 ? i2  : i3;
    float adw = 0.f, mw = 0.f, iw = 0.f;
    if (l < 5) {
      adw = l == 0 ? ad0 : l == 1 ? ad1 : l == 2 ? ad2 : l == 3 ? ad3 : ad4;
      mw  = l == 0 ? m0  : l == 1 ? m1  : l == 2 ? m2  : l == 3 ? m3  : m4;
      iw  = l == 0 ? i0  : l == 1 ? i1  : l == 2 ? i2  : l == 3 ? i3  : i4;
    }
    for (int s = 0; s < deg; ++s) {
      const int p = off + s;
      const int srcs = csr_src[p];
      const unsigned xb = (unsigned)srcs * XSTR;
      const float* ap = (const float*)(xlh + xb + 160);
      const float aA = __expf(lrelu2(ap[hA] + adA) - mA) * iA;
      const ushort2 u2 = *(const ushort2*)(xlh + xb + 2 * l);
      accx += b2f(u2.x) * aA;
      accy += b2f(u2.y) * aA;
      if (l < 32) {
        const float aC = __expf(lrelu2(ap[4] + ad4) - m4) * i4;
        accz += b2f(xlh[xb + 128 + l]) * aC;
      }
      if (l < 5) {
        alpha_out[(long)csr_eid[p] * 5 + l] = __expf(lrelu2(ap[l] + adw) - mw) * iw;
      }
    }
  }

  // epilogue (bf16 store)
  const int c0 = 2 * l, c2 = 128 + l;
  float v0 = accx + bias[c0];     v0 = v0 > 0.f ? v0 : 0.01f * v0;
  float v1 = accy + bias[c0 + 1]; v1 = v1 > 0.f ? v1 : 0.01f * v1;
  float v2 = 0.f;
  if (l < 32) { v2 = accz + bias[c2]; v2 = v2 > 0.f ? v2 : 0.01f * v2; }

  const long hb = (long)n * HID;
  if (DO_LN) {
    const float tot = wsum(v0 + v1 + v2);
    const float mean = tot * (1.f / 160.f);
    const float d0 = v0 - mean, d1 = v1 - mean;
    float sq = d0 * d0 + d1 * d1;
    float d2 = 0.f;
    if (l < 32) { d2 = v2 - mean; sq += d2 * d2; }
    const float var = wsum(sq) * (1.f / 160.f);
    const float rstd = rsqrtf(var + 1e-5f);
    hout[hb + c0]     = f2b(d0 * rstd * gamma_[c0]     + beta_[c0]);
    hout[hb + c0 + 1] = f2b(d1 * rstd * gamma_[c0 + 1] + beta_[c0 + 1]);
    if (l < 32) hout[hb + c2] = f2b(d2 * rstd * gamma_[c2] + beta_[c2]);
  } else {
    hout[hb + c0]     = f2b(v0);
    hout[hb + c0 + 1] = f2b(v1);
    if (l < 32) hout[hb + c2] = f2b(v2);
  }
}

extern "C" void kernel_launch(void* const* d_in, const int* in_sizes, int n_in,
                              void* d_out, int out_size, void* d_ws, size_t ws_size,
                              hipStream_t stream)
{
  const float* x     = (const float*)d_in[0];
  const int*   ei    = (const int*)d_in[1];
  const float* W1    = (const float*)d_in[2];
  const float* att1s = (const float*)d_in[3];
  const float* att1d = (const float*)d_in[4];
  const float* b1    = (const float*)d_in[5];
  const float* g1    = (const float*)d_in[6];
  const float* be1   = (const float*)d_in[7];
  const float* W2    = (const float*)d_in[8];
  const float* att2s = (const float*)d_in[9];
  const float* att2d = (const float*)d_in[10];
  const float* b2    = (const float*)d_in[11];
  const float* Wm    = (const float*)d_in[12];
  const float* bm    = (const float*)d_in[13];

  float* out    = (float*)d_out;                      // [N,160]
  float* alpha1 = out + (long)N_NODES * HID;          // [E,5]
  float* alpha2 = alpha1 + (long)E_TOT * 5;           // [E,5]

  char* p = (char*)d_ws;
  auto alloc = [&](size_t bytes) { void* r = (void*)p; p += (bytes + 255) & ~(size_t)255; return r; };
  unsigned short* hb16 = (unsigned short*)alloc((size_t)N_NODES * HID * 2);
  unsigned short* xlh  = (unsigned short*)alloc((size_t)N_NODES * XSTR * 2);
  float* ad_  = (float*)alloc((size_t)N_NODES * 5 * 4);
  int* deg    = (int*)alloc((size_t)N_NODES * 4);
  int* fillc  = (int*)alloc((size_t)N_NODES * 4);
  int* off    = (int*)alloc((size_t)(N_NODES + 1) * 4);
  int* csrS   = (int*)alloc((size_t)E_TOT * 4);
  int* csrE   = (int*)alloc((size_t)E_TOT * 4);
  int* flag   = (int*)alloc(256);
  unsigned short* Bt1 = (unsigned short*)alloc((size_t)HID * 512 * 2);
  unsigned short* Bt2 = (unsigned short*)alloc((size_t)HID * 192 * 2);
  unsigned short* Btm = (unsigned short*)alloc((size_t)HID * 192 * 2);

  hipMemsetAsync(deg, 0, (size_t)N_NODES * 4, stream);
  hipMemsetAsync(fillc, 0, (size_t)N_NODES * 4, stream);

  detect_kernel<<<1, 64, 0, stream>>>(ei, flag);
  const int EB = (E_TOT + 255) / 256;
  count_kernel<<<EB, 256, 0, stream>>>(ei, flag, deg);
  scan_kernel<<<1, 1024, 0, stream>>>(deg, off);
  fill_kernel<<<EB, 256, 0, stream>>>(ei, flag, off, fillc, csrS, csrE);

  convert_all<<<(HID * 512 + 255) / 256, 256, 0, stream>>>(W1, W2, Wm, Bt1, Bt2, Btm);

  const int GB = (N_NODES + 31) / 32;

  // layer 1: bf16 pipelined LDS-GEMM (BM=32, BK=64 — best measured) + att dots
  gemm_lds<float, F_IN_K, 512, 64, 2><<<GB, 128, 0, stream>>>(x, Bt1, nullptr, xlh, nullptr, att1s, att1d, ad_);
  node_kernel<1><<<N_NODES / 4, 256, 0, stream>>>(off, csrS, csrE, xlh, ad_, alpha1, b1, g1, be1, hb16);

  // layer 2
  gemm_lds<unsigned short, HID, 192, 64, 2><<<GB, 128, 0, stream>>>(hb16, Bt2, nullptr, xlh, nullptr, att2s, att2d, ad_);
  node_kernel<0><<<N_NODES / 4, 256, 0, stream>>>(off, csrS, csrE, xlh, ad_, alpha2, b2, nullptr, nullptr, hb16);

  // final MLP: out = leaky(h2 @ Wm + bm)
  gemm_lds<unsigned short, HID, 192, 64, 1><<<GB, 128, 0, stream>>>(hb16, Btm, out, nullptr, bm, nullptr, nullptr, nullptr);
}

// Round 17
// 396.568 us; speedup vs baseline: 1.0357x; 1.0075x over previous
//
#include <hip/hip_runtime.h>

#define N_NODES 50000
#define E_RAW_N 800000
#define E_TOT   850000
#define F_IN_K  500
#define HID     160
#define XSTR    192   // packed row: 160 bf16 cols + 5 f32 a_s; 384B = 3 L2 lines
#define CHELEMS (HID * 32)   // elements per B chunk (BK=32)

using short8 = __attribute__((ext_vector_type(8))) short;
using f32x4  = __attribute__((ext_vector_type(4))) float;

__device__ __forceinline__ float b2f(unsigned short u) {
  union { unsigned int i; float f; } v; v.i = ((unsigned int)u) << 16; return v.f;
}
__device__ __forceinline__ unsigned short f2b(float f) {
  union { float f; unsigned int i; } v; v.f = f;
  unsigned int i = v.i;
  unsigned int lsb = (i >> 16) & 1u;
  i += 0x7fffu + lsb;
  return (unsigned short)(i >> 16);
}

__device__ __forceinline__ float wsum(float x) {
  #pragma unroll
  for (int o = 32; o; o >>= 1) x += __shfl_xor(x, o, 64);
  return x;
}
__device__ __forceinline__ float wmax(float x) {
  #pragma unroll
  for (int o = 32; o; o >>= 1) x = fmaxf(x, __shfl_xor(x, o, 64));
  return x;
}
__device__ __forceinline__ float lrelu2(float x) { return x > 0.f ? x : 0.2f * x; }

// async 16B/lane global->LDS copy: LDS dest = wave-uniform base + lane*16
__device__ __forceinline__ void gload16(const unsigned short* g, unsigned short* l) {
  __builtin_amdgcn_global_load_lds(
      (const __attribute__((address_space(1))) void*)g,
      (__attribute__((address_space(3))) void*)l, 16, 0, 0);
}

// swizzled element index within a 5120-elem chunk (bijective; read==write perm)
__device__ __forceinline__ int bswz(int c, int kk) {
  return ((c << 5) | kk) ^ ((c & 7) << 3);
}

// ---------------- edge dtype detection (int64 vs int32 hedge) ----------------
__global__ void detect_kernel(const int* __restrict__ ei, int* __restrict__ flag) {
  if (threadIdx.x == 0 && blockIdx.x == 0) {
    int allz = 1;
    for (int i = 1; i < 128; i += 2) if (ei[i] != 0) { allz = 0; break; }
    *flag = allz;  // 1 => int64 layout
  }
}
__device__ __forceinline__ int edge_src(const int* ei, int wide, int e) {
  return wide ? ei[2 * e] : ei[e];
}
__device__ __forceinline__ int edge_dst(const int* ei, int wide, int e) {
  return wide ? ei[2 * (E_RAW_N + e)] : ei[E_RAW_N + e];
}

// ------- weight pre-convert: f32 -> bf16, chunked + XOR-swizzled layout -------
__global__ __launch_bounds__(256) void convert_all(
    const float* __restrict__ W1, const float* __restrict__ W2, const float* __restrict__ Wm,
    unsigned short* __restrict__ Bt1, unsigned short* __restrict__ Bt2,
    unsigned short* __restrict__ Btm)
{
  const int i = blockIdx.x * 256 + threadIdx.x;
  if (i < HID * 512) {
    const int c = i / 512, k = i % 512;
    const int idx = (k >> 5) * CHELEMS + bswz(c, k & 31);
    Bt1[idx] = f2b((k < F_IN_K) ? W1[(long)k * HID + c] : 0.f);
  }
  if (i < HID * 192) {
    const int c = i / 192, k = i % 192;
    const int idx = (k >> 5) * CHELEMS + bswz(c, k & 31);
    Bt2[idx] = f2b((k < HID) ? W2[(long)k * HID + c] : 0.f);
    Btm[idx] = f2b((k < HID) ? Wm[(long)k * HID + c] : 0.f);
  }
}

// ---------------- GEMM: [M,160] = A[M,K] @ B ---------------------------------
// block = 2 waves (128 thr), BM=32; wave = 16 rows x 160 cols, 16x16x32 MFMA.
// B staged via global_load_lds into double-buffered LDS (pre-swizzled Bt ->
// linear async copy, XOR-swizzled ds_read_b128, 2-way banks = free).
// One barrier per chunk; next chunk's loads fly under current compute.
// AT=float: A converted to bf16 in-register. AT=ushort: direct short8 loads.
// MODE 1: +bias, leaky(0.01), C f32. MODE 2: packed row (XSTR) + att dots.
template<typename AT, int K, int KPAD, int MODE>
__global__ __launch_bounds__(128) void gemm_lds(
    const AT* __restrict__ A, const unsigned short* __restrict__ Bt,
    float* __restrict__ C, unsigned short* __restrict__ Ch,
    const float* __restrict__ bias,
    const float* __restrict__ att_s, const float* __restrict__ att_d,
    float* __restrict__ a_d)
{
  constexpr bool AB16 = (sizeof(AT) == 2);
  constexpr int CHUNKS = KPAD / 32;
  __shared__ __align__(16) unsigned short Bs[2][CHELEMS];

  const int t = threadIdx.x;
  const int l = t & 63;
  const int w = t >> 6;
  const int m = l & 15;
  const int kgrp = (l >> 4) * 8;
  const int rbase = blockIdx.x * 32 + w * 16;
  const int arow = (rbase + m < N_NODES) ? rbase + m : N_NODES - 1;
  const AT* Arow = A + (long)arow * K;

  f32x4 acc[10];
  #pragma unroll
  for (int i = 0; i < 10; ++i) acc[i] = (f32x4){0.f, 0.f, 0.f, 0.f};

  float  arF[8], arF2[8];
  short8 arS, arS2;

  auto issueB = [&](int cc) {
    const unsigned short* src = Bt + (long)cc * CHELEMS;
    unsigned short* dst = &Bs[cc & 1][0];
    #pragma unroll
    for (int j = 0; j < 5; ++j) {
      const int base = (j * 2 + w) * 512;   // 1KB per wave-instruction
      gload16(src + base + l * 8, dst + base);
    }
  };
  auto loadA = [&](int cc, float* aF, short8& aS) {
    const int kb = cc * 32 + kgrp;
    if constexpr (AB16) {
      short8 v = (short8){0,0,0,0,0,0,0,0};
      if (kb + 8 <= K) v = *(const short8*)(Arow + kb);
      else if (kb < K) {
        #pragma unroll
        for (int j = 0; j < 8; ++j) v[j] = (kb + j < K) ? (short)Arow[kb + j] : (short)0;
      }
      aS = v;
    } else {
      if (kb + 8 <= K) {
        const float4 a0 = *(const float4*)(Arow + kb);
        const float4 a1 = *(const float4*)(Arow + kb + 4);
        aF[0]=a0.x; aF[1]=a0.y; aF[2]=a0.z; aF[3]=a0.w;
        aF[4]=a1.x; aF[5]=a1.y; aF[6]=a1.z; aF[7]=a1.w;
      } else {
        #pragma unroll
        for (int j = 0; j < 8; ++j) aF[j] = (kb + j < K) ? (float)Arow[kb + j] : 0.f;
      }
    }
  };

  issueB(0);
  loadA(0, arF, arS);

  for (int cc = 0; cc < CHUNKS; ++cc) {
    __syncthreads();   // drains vmcnt -> buf[cc&1] valid for all waves
    if (cc + 1 < CHUNKS) {
      issueB(cc + 1);                      // flies under compute(cc)
      loadA(cc + 1, arF2, arS2);
      __builtin_amdgcn_sched_barrier(0);   // pin load issue before MFMA cluster
    }
    __builtin_amdgcn_s_setprio(1);
    short8 ah;
    if constexpr (AB16) {
      ah = arS;
    } else {
      #pragma unroll
      for (int j = 0; j < 8; ++j) ah[j] = (short)f2b(arF[j]);
    }
    #pragma unroll
    for (int ct = 0; ct < 10; ++ct) {
      const int c = ct * 16 + m;
      const short8 bh = *(const short8*)&Bs[cc & 1][bswz(c, kgrp)];
      acc[ct] = __builtin_amdgcn_mfma_f32_16x16x32_bf16(ah, bh, acc[ct], 0, 0, 0);
    }
    __builtin_amdgcn_s_setprio(0);
    if (cc + 1 < CHUNKS) {
      if constexpr (AB16) arS = arS2;
      else {
        #pragma unroll
        for (int j = 0; j < 8; ++j) arF[j] = arF2[j];
      }
    }
  }

  const int crow0 = rbase + (l >> 4) * 4;

  if (MODE == 2) {
    // fused attention dots; a_s packed into row tail, a_d to its own array
    #pragma unroll
    for (int r = 0; r < 4; ++r) {
      float ps[5], pd[5];
      #pragma unroll
      for (int h = 0; h < 5; ++h) {
        float s = acc[2*h][r]     * att_s[(2*h) * 16 + m]
                + acc[2*h + 1][r] * att_s[(2*h + 1) * 16 + m];
        float d = acc[2*h][r]     * att_d[(2*h) * 16 + m]
                + acc[2*h + 1][r] * att_d[(2*h + 1) * 16 + m];
        #pragma unroll
        for (int o = 1; o < 16; o <<= 1) {
          s += __shfl_xor(s, o, 64);
          d += __shfl_xor(d, o, 64);
        }
        ps[h] = s; pd[h] = d;
      }
      const int crow = crow0 + r;
      if (crow < N_NODES && m < 5) {
        const float vs = m == 0 ? ps[0] : m == 1 ? ps[1] : m == 2 ? ps[2] : m == 3 ? ps[3] : ps[4];
        const float vd = m == 0 ? pd[0] : m == 1 ? pd[1] : m == 2 ? pd[2] : m == 3 ? pd[3] : pd[4];
        ((float*)(Ch + (long)crow * XSTR + 160))[m] = vs;
        a_d[crow * 5 + m] = vd;
      }
    }
  }

  #pragma unroll
  for (int r = 0; r < 4; ++r) {
    const int crow = crow0 + r;
    if (crow < N_NODES) {
      #pragma unroll
      for (int ct = 0; ct < 10; ++ct) {
        const int col = ct * 16 + m;
        float v = acc[ct][r];
        if (MODE == 1) { v += bias[col]; v = v > 0.f ? v : 0.01f * v; }
        if (MODE == 2) Ch[(long)crow * XSTR + col] = f2b(v);
        else           C[(long)crow * HID + col] = v;
      }
    }
  }
}

// ---------------- CSR build ---------------------------------------------------
__global__ __launch_bounds__(256) void count_kernel(const int* __restrict__ ei,
    const int* __restrict__ flag, int* __restrict__ deg) {
  const int e = blockIdx.x * 256 + threadIdx.x;
  if (e >= E_TOT) return;
  const int wide = *flag;
  const int d = (e < E_RAW_N) ? edge_dst(ei, wide, e) : (e - E_RAW_N);
  atomicAdd(&deg[d], 1);
}

#define SCAN_CHUNK 49  // 1024*49 = 50176 >= 50000
__global__ __launch_bounds__(1024) void scan_kernel(const int* __restrict__ deg, int* __restrict__ off) {
  __shared__ int wtot[16];
  const int t = threadIdx.x;
  const int lane = t & 63, wid = t >> 6;
  const int base = t * SCAN_CHUNK;
  int local[SCAN_CHUNK];
  int sum = 0;
  #pragma unroll
  for (int i = 0; i < SCAN_CHUNK; ++i) {
    const int idx = base + i;
    const int v = (idx < N_NODES) ? deg[idx] : 0;
    local[i] = sum;
    sum += v;
  }
  int inc = sum;
  #pragma unroll
  for (int o = 1; o < 64; o <<= 1) {
    const int y = __shfl_up(inc, o, 64);
    if (lane >= o) inc += y;
  }
  if (lane == 63) wtot[wid] = inc;
  __syncthreads();
  if (wid == 0 && lane < 16) {
    const int v = wtot[lane];
    int inc2 = v;
    #pragma unroll
    for (int o = 1; o < 16; o <<= 1) {
      const int y = __shfl_up(inc2, o, 64);
      if (lane >= o) inc2 += y;
    }
    wtot[lane] = inc2 - v;  // exclusive
  }
  __syncthreads();
  const int pre = wtot[wid] + (inc - sum);
  #pragma unroll
  for (int i = 0; i < SCAN_CHUNK; ++i) {
    const int idx = base + i;
    if (idx < N_NODES) off[idx] = pre + local[i];
  }
  if (t == 1023) off[N_NODES] = E_TOT;
}

__global__ __launch_bounds__(256) void fill_kernel(const int* __restrict__ ei,
    const int* __restrict__ flag, const int* __restrict__ off,
    int* __restrict__ fillc, int* __restrict__ csr_src, int* __restrict__ csr_eid) {
  const int e = blockIdx.x * 256 + threadIdx.x;
  if (e >= E_TOT) return;
  const int wide = *flag;
  int s, d;
  if (e < E_RAW_N) { s = edge_src(ei, wide, e); d = edge_dst(ei, wide, e); }
  else { s = e - E_RAW_N; d = s; }
  const int p = off[d] + atomicAdd(&fillc[d], 1);
  csr_src[p] = s;
  csr_eid[p] = e;
}

// ---------------- fused per-node segment-softmax + aggregation ---------------
// xlh rows packed (XSTR=192, 384B = 3 cache lines): bf16 cols [0..160) +
// a_s f32 at [160..170). Fast path (deg<=64): register softmax (no max pass);
// edge table in LDS; unroll-8 gather.
template<int DO_LN>
__global__ __launch_bounds__(256) void node_kernel(
    const int* __restrict__ off_, const int* __restrict__ csr_src, const int* __restrict__ csr_eid,
    const unsigned short* __restrict__ xlh,
    const float* __restrict__ a_d,
    float* __restrict__ alpha_out,
    const float* __restrict__ bias,
    const float* __restrict__ gamma_, const float* __restrict__ beta_,
    unsigned short* __restrict__ hout)
{
  __shared__ int   srcS[4][64];
  __shared__ float alS[4][64][6];

  const int w = threadIdx.x >> 6;
  const int l = threadIdx.x & 63;
  const int n = blockIdx.x * 4 + w;
  if (n >= N_NODES) return;
  const int off = off_[n];
  const int deg = off_[n + 1] - off;

  const float ad0 = a_d[n*5+0], ad1 = a_d[n*5+1], ad2 = a_d[n*5+2], ad3 = a_d[n*5+3], ad4 = a_d[n*5+4];
  const int hA = l >> 4;  // head for cols 2l, 2l+1
  float accx = 0.f, accy = 0.f, accz = 0.f;

  if (deg <= 64) {
    // ---- register softmax (no max pass): one lane per edge ----
    int src = 0, eid = 0;
    float e0 = 0.f, e1 = 0.f, e2 = 0.f, e3 = 0.f, e4 = 0.f;
    if (l < deg) {
      src = csr_src[off + l];
      eid = csr_eid[off + l];
      const float* ap = (const float*)(xlh + (unsigned)src * XSTR + 160);
      e0 = __expf(lrelu2(ap[0] + ad0));
      e1 = __expf(lrelu2(ap[1] + ad1));
      e2 = __expf(lrelu2(ap[2] + ad2));
      e3 = __expf(lrelu2(ap[3] + ad3));
      e4 = __expf(lrelu2(ap[4] + ad4));
    }
    const float i0 = 1.f / (wsum(e0) + 1e-16f), i1 = 1.f / (wsum(e1) + 1e-16f),
                i2 = 1.f / (wsum(e2) + 1e-16f), i3 = 1.f / (wsum(e3) + 1e-16f),
                i4 = 1.f / (wsum(e4) + 1e-16f);
    const float a0 = e0 * i0, a1 = e1 * i1, a2 = e2 * i2, a3 = e3 * i3, a4 = e4 * i4;
    if (l < deg) {
      float* aw = alpha_out + (long)eid * 5;
      aw[0] = a0; aw[1] = a1; aw[2] = a2; aw[3] = a3; aw[4] = a4;
    }
    srcS[w][l] = src;
    alS[w][l][0] = a0; alS[w][l][1] = a1; alS[w][l][2] = a2;
    alS[w][l][3] = a3; alS[w][l][4] = a4;

    const int degR = (deg + 7) & ~7;
    const unsigned cx = 2 * l, cz = 128 + l;
    for (int s0 = 0; s0 < degR; s0 += 8) {
      int sr[8]; float aA[8], aB[8];
      #pragma unroll
      for (int j = 0; j < 8; ++j) {
        sr[j] = srcS[w][s0 + j];
        aA[j] = alS[w][s0 + j][hA];
        aB[j] = alS[w][s0 + j][4];
      }
      ushort2 u2[8]; unsigned short z[8];
      #pragma unroll
      for (int j = 0; j < 8; ++j) {
        const unsigned xb = (unsigned)sr[j] * XSTR;
        u2[j] = *(const ushort2*)(xlh + xb + cx);
        if (l < 32) z[j] = xlh[xb + cz];
      }
      #pragma unroll
      for (int j = 0; j < 8; ++j) {
        accx += b2f(u2[j].x) * aA[j];
        accy += b2f(u2[j].y) * aA[j];
        if (l < 32) accz += b2f(z[j]) * aB[j];
      }
    }
  } else {
    // ---- slow path (rare): 3-pass over segment ----
    float m0 = -1e30f, m1 = -1e30f, m2 = -1e30f, m3 = -1e30f, m4 = -1e30f;
    for (int s = l; s < deg; s += 64) {
      const float* ap = (const float*)(xlh + (unsigned)csr_src[off + s] * XSTR + 160);
      m0 = fmaxf(m0, lrelu2(ap[0] + ad0));
      m1 = fmaxf(m1, lrelu2(ap[1] + ad1));
      m2 = fmaxf(m2, lrelu2(ap[2] + ad2));
      m3 = fmaxf(m3, lrelu2(ap[3] + ad3));
      m4 = fmaxf(m4, lrelu2(ap[4] + ad4));
    }
    m0 = wmax(m0); m1 = wmax(m1); m2 = wmax(m2); m3 = wmax(m3); m4 = wmax(m4);
    float s0 = 0.f, s1 = 0.f, s2 = 0.f, s3 = 0.f, s4 = 0.f;
    for (int s = l; s < deg; s += 64) {
      const float* ap = (const float*)(xlh + (unsigned)csr_src[off + s] * XSTR + 160);
      s0 += __expf(lrelu2(ap[0] + ad0) - m0);
      s1 += __expf(lrelu2(ap[1] + ad1) - m1);
      s2 += __expf(lrelu2(ap[2] + ad2) - m2);
      s3 += __expf(lrelu2(ap[3] + ad3) - m3);
      s4 += __expf(lrelu2(ap[4] + ad4) - m4);
    }
    const float i0 = 1.f / (wsum(s0) + 1e-16f), i1 = 1.f / (wsum(s1) + 1e-16f),
                i2 = 1.f / (wsum(s2) + 1e-16f), i3 = 1.f / (wsum(s3) + 1e-16f),
                i4 = 1.f / (wsum(s4) + 1e-16f);
    const float adA = hA == 0 ? ad0 : hA == 1 ? ad1 : hA == 2 ? ad2 : ad3;
    const float mA  = hA == 0 ? m0  : hA == 1 ? m1  : hA == 2 ? m2  : m3;
    const float iA  = hA == 0 ? i0  : hA == 1 ? i1  : hA == 2 ? i2  : i3;
    float adw = 0.f, mw = 0.f, iw = 0.f;
    if (l < 5) {
      adw = l == 0 ? ad0 : l == 1 ? ad1 : l == 2 ? ad2 : l == 3 ? ad3 : ad4;
      mw  = l == 0 ? m0  : l == 1 ? m1  : l == 2 ? m2  : l == 3 ? m3  : m4;
      iw  = l == 0 ? i0  : l == 1 ? i1  : l == 2 ? i2  : l == 3 ? i3  : i4;
    }
    for (int s = 0; s < deg; ++s) {
      const int p = off + s;
      const int srcs = csr_src[p];
      const unsigned xb = (unsigned)srcs * XSTR;
      const float* ap = (const float*)(xlh + xb + 160);
      const float aA = __expf(lrelu2(ap[hA] + adA) - mA) * iA;
      const ushort2 u2 = *(const ushort2*)(xlh + xb + 2 * l);
      accx += b2f(u2.x) * aA;
      accy += b2f(u2.y) * aA;
      if (l < 32) {
        const float aC = __expf(lrelu2(ap[4] + ad4) - m4) * i4;
        accz += b2f(xlh[xb + 128 + l]) * aC;
      }
      if (l < 5) {
        alpha_out[(long)csr_eid[p] * 5 + l] = __expf(lrelu2(ap[l] + adw) - mw) * iw;
      }
    }
  }

  // epilogue (bf16 store)
  const int c0 = 2 * l, c2 = 128 + l;
  float v0 = accx + bias[c0];     v0 = v0 > 0.f ? v0 : 0.01f * v0;
  float v1 = accy + bias[c0 + 1]; v1 = v1 > 0.f ? v1 : 0.01f * v1;
  float v2 = 0.f;
  if (l < 32) { v2 = accz + bias[c2]; v2 = v2 > 0.f ? v2 : 0.01f * v2; }

  const long hb = (long)n * HID;
  if (DO_LN) {
    const float tot = wsum(v0 + v1 + v2);
    const float mean = tot * (1.f / 160.f);
    const float d0 = v0 - mean, d1 = v1 - mean;
    float sq = d0 * d0 + d1 * d1;
    float d2 = 0.f;
    if (l < 32) { d2 = v2 - mean; sq += d2 * d2; }
    const float var = wsum(sq) * (1.f / 160.f);
    const float rstd = rsqrtf(var + 1e-5f);
    hout[hb + c0]     = f2b(d0 * rstd * gamma_[c0]     + beta_[c0]);
    hout[hb + c0 + 1] = f2b(d1 * rstd * gamma_[c0 + 1] + beta_[c0 + 1]);
    if (l < 32) hout[hb + c2] = f2b(d2 * rstd * gamma_[c2] + beta_[c2]);
  } else {
    hout[hb + c0]     = f2b(v0);
    hout[hb + c0 + 1] = f2b(v1);
    if (l < 32) hout[hb + c2] = f2b(v2);
  }
}

extern "C" void kernel_launch(void* const* d_in, const int* in_sizes, int n_in,
                              void* d_out, int out_size, void* d_ws, size_t ws_size,
                              hipStream_t stream)
{
  const float* x     = (const float*)d_in[0];
  const int*   ei    = (const int*)d_in[1];
  const float* W1    = (const float*)d_in[2];
  const float* att1s = (const float*)d_in[3];
  const float* att1d = (const float*)d_in[4];
  const float* b1    = (const float*)d_in[5];
  const float* g1    = (const float*)d_in[6];
  const float* be1   = (const float*)d_in[7];
  const float* W2    = (const float*)d_in[8];
  const float* att2s = (const float*)d_in[9];
  const float* att2d = (const float*)d_in[10];
  const float* b2    = (const float*)d_in[11];
  const float* Wm    = (const float*)d_in[12];
  const float* bm    = (const float*)d_in[13];

  float* out    = (float*)d_out;                      // [N,160]
  float* alpha1 = out + (long)N_NODES * HID;          // [E,5]
  float* alpha2 = alpha1 + (long)E_TOT * 5;           // [E,5]

  char* p = (char*)d_ws;
  auto alloc = [&](size_t bytes) { void* r = (void*)p; p += (bytes + 255) & ~(size_t)255; return r; };
  unsigned short* hb16 = (unsigned short*)alloc((size_t)N_NODES * HID * 2);
  unsigned short* xlh  = (unsigned short*)alloc((size_t)N_NODES * XSTR * 2);
  float* ad_  = (float*)alloc((size_t)N_NODES * 5 * 4);
  int* deg    = (int*)alloc((size_t)N_NODES * 4);
  int* fillc  = (int*)alloc((size_t)N_NODES * 4);
  int* off    = (int*)alloc((size_t)(N_NODES + 1) * 4);
  int* csrS   = (int*)alloc((size_t)E_TOT * 4);
  int* csrE   = (int*)alloc((size_t)E_TOT * 4);
  int* flag   = (int*)alloc(256);
  unsigned short* Bt1 = (unsigned short*)alloc((size_t)HID * 512 * 2);
  unsigned short* Bt2 = (unsigned short*)alloc((size_t)HID * 192 * 2);
  unsigned short* Btm = (unsigned short*)alloc((size_t)HID * 192 * 2);

  // deg and fillc are adjacent allocations -> one memset covers both
  hipMemsetAsync(deg, 0, (size_t)((char*)off - (char*)deg), stream);

  detect_kernel<<<1, 64, 0, stream>>>(ei, flag);
  const int EB = (E_TOT + 255) / 256;
  count_kernel<<<EB, 256, 0, stream>>>(ei, flag, deg);
  scan_kernel<<<1, 1024, 0, stream>>>(deg, off);
  fill_kernel<<<EB, 256, 0, stream>>>(ei, flag, off, fillc, csrS, csrE);

  convert_all<<<(HID * 512 + 255) / 256, 256, 0, stream>>>(W1, W2, Wm, Bt1, Bt2, Btm);

  const int GB = (N_NODES + 31) / 32;

  // layer 1: async-staged bf16 GEMM (global_load_lds, swizzled Bt) + att dots
  gemm_lds<float, F_IN_K, 512, 2><<<GB, 128, 0, stream>>>(x, Bt1, nullptr, xlh, nullptr, att1s, att1d, ad_);
  node_kernel<1><<<N_NODES / 4, 256, 0, stream>>>(off, csrS, csrE, xlh, ad_, alpha1, b1, g1, be1, hb16);

  // layer 2
  gemm_lds<unsigned short, HID, 192, 2><<<GB, 128, 0, stream>>>(hb16, Bt2, nullptr, xlh, nullptr, att2s, att2d, ad_);
  node_kernel<0><<<N_NODES / 4, 256, 0, stream>>>(off, csrS, csrE, xlh, ad_, alpha2, b2, nullptr, nullptr, hb16);

  // final MLP: out = leaky(h2 @ Wm + bm)
  gemm_lds<unsigned short, HID, 192, 1><<<GB, 128, 0, stream>>>(hb16, Btm, out, nullptr, bm, nullptr, nullptr, nullptr);
}